// Round 2
// baseline (5080.979 us; speedup 1.0000x reference)
//
#include <hip/hip_runtime.h>

#define NS 16
#define NB 16
#define NK 3
#define NT 20
#define TH 10
#define FPX 64
#define DPX 28
#define CPX 37
#define NP 1369
#define NH 256
#define NHH 128

// dynamic LDS layout (float offsets)
#define O_MAPS   0                   // [TH][NP] raw conv maps
#define O_EB     (O_MAPS + TH*NP)    // [TH][NP] exp buf / diff buf; aliased as frame tile in phase 1
#define O_PREV   (O_EB + TH*NP)      // [NP] last map of previous half
#define O_TMPL   (O_PREV + NP)       // [DPX*DPX]
#define O_HID    (O_TMPL + DPX*DPX)  // [TH][NH]
#define O_DH1    (O_HID + TH*NH)     // [TH][NH]
#define O_MIDM   (O_DH1 + TH*NH)     // [TH][NHH]
#define O_MIDS   (O_MIDM + TH*NHH)   // [TH][NHH]
#define O_MIDD   (O_MIDS + TH*NHH)   // [TH][NHH]
#define O_STAT   (O_MIDD + TH*NHH)   // inv[TH] + red[8]
#define POOL_FLOATS (O_STAT + 32)

__global__ __launch_bounds__(256)
void enc_fused(const float* __restrict__ frames, const float* __restrict__ digit,
               const float* __restrict__ w_h1, const float* __restrict__ b_h1,
               const float* __restrict__ wm1,  const float* __restrict__ bm1,
               const float* __restrict__ wm2,  const float* __restrict__ bm2,
               const float* __restrict__ ws1,  const float* __restrict__ bs1,
               const float* __restrict__ ws2,  const float* __restrict__ bs2,
               const float* __restrict__ wd1,  const float* __restrict__ bd1,
               const float* __restrict__ wd2,  const float* __restrict__ bd2,
               const float* __restrict__ wd3,  const float* __restrict__ bd3,
               float* __restrict__ out)
{
    extern __shared__ float pool[];
    const int tid  = threadIdx.x;
    const int lane = tid & 63;
    const int wv   = tid >> 6;

    const int blk = blockIdx.x;          // ((s*NB + b)*NK + k)
    const int k   = blk % NK;
    const int sb  = blk / NK;
    const int b   = sb % NB;
    const int s   = sb / NB;

    float* maps  = pool + O_MAPS;
    float* ebuf  = pool + O_EB;
    float* prevl = pool + O_PREV;
    float* tmpl  = pool + O_TMPL;
    float* hidb  = pool + O_HID;
    float* dh1b  = pool + O_DH1;
    float* midm  = pool + O_MIDM;
    float* midsb = pool + O_MIDS;
    float* midd  = pool + O_MIDD;
    float* invb  = pool + O_STAT;        // [TH]
    float* red   = pool + O_STAT + TH;   // [8]

    // stage template once per block
    const float* dg = digit + (size_t)((s * NB + b) * NK + k) * (DPX * DPX);
    for (int i = tid; i < DPX * DPX; i += 256) tmpl[i] = dg[i];

    for (int half = 0; half < 2; ++half) {
        const int t0 = half * TH;
        float* fr = ebuf;   // frame tile aliases ebuf (phase-1 only use)

        // ---- phase 1: correlation, 10 timesteps into maps[] ----
        for (int tl = 0; tl < TH; ++tl) {
            __syncthreads();  // fr (and on 2nd half: ebuf/maps) reuse
            const float* fp = frames + (size_t)(b * NT + t0 + tl) * (FPX * FPX);
            for (int idx = tid; idx < FPX * FPX; idx += 256)
                fr[(idx >> 6) * 65 + (idx & 63)] = fp[idx];
            __syncthreads();

            float* cur = maps + tl * NP;
            for (int task = tid; task < 259; task += 256) {
                int g  = task / 37;
                int i  = task - g * 37;
                int j0 = g * 6;
                float a0 = 0.f, a1 = 0.f, a2 = 0.f, a3 = 0.f, a4 = 0.f, a5 = 0.f;
                for (int u = 0; u < DPX; ++u) {
                    const float* frow = &fr[(i + u) * 65 + j0];
                    float w[34];
#pragma unroll
                    for (int x = 0; x < 34; ++x) w[x] = frow[x];
#pragma unroll
                    for (int v = 0; v < DPX; ++v) {
                        float tv = tmpl[u * DPX + v];   // wave-uniform broadcast
                        a0 = fmaf(w[v + 0], tv, a0);
                        a1 = fmaf(w[v + 1], tv, a1);
                        a2 = fmaf(w[v + 2], tv, a2);
                        a3 = fmaf(w[v + 3], tv, a3);
                        a4 = fmaf(w[v + 4], tv, a4);
                        a5 = fmaf(w[v + 5], tv, a5);
                    }
                }
                int base = i * CPX + j0;
                cur[base + 0] = a0;
                if (g != 6) {
                    cur[base + 1] = a1; cur[base + 2] = a2; cur[base + 3] = a3;
                    cur[base + 4] = a4; cur[base + 5] = a5;
                }
            }
        }
        __syncthreads();

        // ---- phase 2: per-t softmax stats; ebuf <- exp(conv - max) ----
        for (int tl = 0; tl < TH; ++tl) {
            const float* cur = maps + tl * NP;
            float lmax = -3.0e38f;
            for (int p = tid; p < NP; p += 256) lmax = fmaxf(lmax, cur[p]);
            for (int o = 32; o; o >>= 1) lmax = fmaxf(lmax, __shfl_xor(lmax, o, 64));
            if (lane == 0) red[wv] = lmax;
            __syncthreads();
            const float mx = fmaxf(fmaxf(red[0], red[1]), fmaxf(red[2], red[3]));
            float lsum = 0.f;
            for (int p = tid; p < NP; p += 256) {
                float e = __expf(cur[p] - mx);
                ebuf[tl * NP + p] = e;
                lsum += e;
            }
            for (int o = 32; o; o >>= 1) lsum += __shfl_xor(lsum, o, 64);
            if (lane == 0) red[4 + wv] = lsum;
            __syncthreads();
            if (tid == 0) invb[tl] = 1.0f / (red[4] + red[5] + red[6] + red[7]);
            __syncthreads();
        }

        // ---- phase 3: hidden = relu(softmax @ w_h1 + b), batched over 10 t ----
        {
            float acc[TH];
#pragma unroll
            for (int i = 0; i < TH; ++i) acc[i] = 0.f;
            const float* wc = w_h1 + tid;
#pragma unroll 2
            for (int p = 0; p < NP; ++p) {
                float w = wc[(size_t)p * NH];
#pragma unroll
                for (int tl = 0; tl < TH; ++tl)
                    acc[tl] = fmaf(ebuf[tl * NP + p], w, acc[tl]);
            }
            float bb = b_h1[tid];
#pragma unroll
            for (int tl = 0; tl < TH; ++tl) {
                float v = acc[tl] * invb[tl] + bb;
                hidb[tl * NH + tid] = v > 0.f ? v : 0.f;
            }
        }
        __syncthreads();

        // ---- phase 3.5: ebuf <- temporal diffs (conv[t] - conv[t-1]) ----
        for (int idx = tid; idx < TH * NP; idx += 256) {
            int tl = idx / NP, p = idx - tl * NP;
            float pv = (tl == 0) ? prevl[p] : maps[(tl - 1) * NP + p];
            float d  = maps[tl * NP + p] - pv;
            if (half == 0 && tl == 0) d = 0.f;   // t=0 has no predecessor
            ebuf[idx] = d;
        }
        __syncthreads();

        // ---- phase 4: dh1 = relu(diff @ wd1 + bd1), batched ----
        {
            float acc[TH];
#pragma unroll
            for (int i = 0; i < TH; ++i) acc[i] = 0.f;
            const float* wc = wd1 + tid;
#pragma unroll 2
            for (int p = 0; p < NP; ++p) {
                float w = wc[(size_t)p * NH];
#pragma unroll
                for (int tl = 0; tl < TH; ++tl)
                    acc[tl] = fmaf(ebuf[tl * NP + p], w, acc[tl]);
            }
            float bb = bd1[tid];
#pragma unroll
            for (int tl = 0; tl < TH; ++tl) {
                float v = acc[tl] + bb;
                dh1b[tl * NH + tid] = v > 0.f ? v : 0.f;
            }
        }
        __syncthreads();

        // ---- phase 5a: mean/std mid layers (waves 0-1: wm1, waves 2-3: ws1) ----
        {
            const int j = tid & 127;
            const float* w1 = (tid < 128) ? wm1 : ws1;
            const float* b1 = (tid < 128) ? bm1 : bs1;
            float* om       = (tid < 128) ? midm : midsb;
            float acc[TH];
#pragma unroll
            for (int i = 0; i < TH; ++i) acc[i] = 0.f;
            const float* wc = w1 + j;
#pragma unroll 2
            for (int h = 0; h < NH; ++h) {
                float w = wc[h * NHH];
#pragma unroll
                for (int tl = 0; tl < TH; ++tl)
                    acc[tl] = fmaf(hidb[tl * NH + h], w, acc[tl]);
            }
            float bb = b1[j];
#pragma unroll
            for (int tl = 0; tl < TH; ++tl) {
                float v = acc[tl] + bb;
                om[tl * NHH + j] = v > 0.f ? v : 0.f;
            }
        }
        // ---- phase 5b: disp mid layer ----
        if (tid < 128) {
            float acc[TH];
#pragma unroll
            for (int i = 0; i < TH; ++i) acc[i] = 0.f;
            const float* wc = wd2 + tid;
#pragma unroll 2
            for (int h = 0; h < NH; ++h) {
                float w = wc[h * NHH];
#pragma unroll
                for (int tl = 0; tl < TH; ++tl)
                    acc[tl] = fmaf(dh1b[tl * NH + h], w, acc[tl]);
            }
            float bb = bd2[tid];
#pragma unroll
            for (int tl = 0; tl < TH; ++tl) {
                float v = acc[tl] + bb;
                midd[tl * NHH + tid] = v > 0.f ? v : 0.f;
            }
        }
        __syncthreads();

        // ---- phase 6: final heads (60 dot products of length 128) ----
        if (tid < 60) {
            const int t_l  = tid / 6, slot = tid % 6;
            const int tg   = t0 + t_l;
            const int d    = slot & 1;
            const int head = slot >> 1;            // 0 mean, 1 std, 2 disp
            if (!(head == 2 && tg == 0)) {
                const float* mb; const float* w2; const float* b2;
                if (head == 0)      { mb = midm;  w2 = wm2; b2 = bm2; }
                else if (head == 1) { mb = midsb; w2 = ws2; b2 = bs2; }
                else                { mb = midd;  w2 = wd3; b2 = bd3; }
                float acc = 0.f;
                for (int j = 0; j < NHH; ++j)
                    acc = fmaf(mb[t_l * NHH + j], w2[j * 2 + d], acc);
                acc += b2[d];
                float r; size_t oi;
                if (head == 0) {
                    r  = tanhf(acc);
                    oi = ((size_t)((s * NB + b) * NT + tg) * NK + k) * 2 + d;
                } else if (head == 1) {
                    r  = expf(acc);
                    oi = (size_t)NS * NB * NT * NK * 2
                       + ((size_t)((s * NB + b) * NT + tg) * NK + k) * 2 + d;
                } else {
                    r  = tanhf(acc);
                    oi = (size_t)NS * NB * NT * NK * 2 * 2
                       + ((size_t)((s * NB + b) * (NT - 1) + (tg - 1)) * NK + k) * 2 + d;
                }
                out[oi] = r;
            }
        }

        // ---- save last map of this half for next half's diff ----
        __syncthreads();
        for (int p = tid; p < NP; p += 256) prevl[p] = maps[(TH - 1) * NP + p];
        __syncthreads();
    }
}

extern "C" void kernel_launch(void* const* d_in, const int* in_sizes, int n_in,
                              void* d_out, int out_size, void* d_ws, size_t ws_size,
                              hipStream_t stream) {
    const float* frames = (const float*)d_in[0];
    const float* digit  = (const float*)d_in[1];
    const float* w_h1   = (const float*)d_in[2];
    const float* b_h1   = (const float*)d_in[3];
    const float* wm1    = (const float*)d_in[4];
    const float* bm1    = (const float*)d_in[5];
    const float* wm2    = (const float*)d_in[6];
    const float* bm2    = (const float*)d_in[7];
    const float* ws1    = (const float*)d_in[8];
    const float* bs1    = (const float*)d_in[9];
    const float* ws2    = (const float*)d_in[10];
    const float* bs2    = (const float*)d_in[11];
    const float* wd1    = (const float*)d_in[12];
    const float* bd1    = (const float*)d_in[13];
    const float* wd2    = (const float*)d_in[14];
    const float* bd2    = (const float*)d_in[15];
    const float* wd3    = (const float*)d_in[16];
    const float* bd3    = (const float*)d_in[17];

    float* o = (float*)d_out;

    dim3 grid(NS * NB * NK);
    dim3 block(256);
    size_t smem = (size_t)POOL_FLOATS * sizeof(float);
    enc_fused<<<grid, block, smem, stream>>>(frames, digit,
        w_h1, b_h1, wm1, bm1, wm2, bm2, ws1, bs1, ws2, bs2,
        wd1, bd1, wd2, bd2, wd3, bd3, o);
}

// Round 3
// 1936.312 us; speedup vs baseline: 2.6241x; 2.6241x over previous
//
#include <hip/hip_runtime.h>

#define NS 16
#define NB 16
#define NK 3
#define NT 20
#define FPX 64
#define DPX 28
#define CPX 37
#define NP 1369
#define NH 256
#define NHH 128

// ---------------- Kernel 1: template correlation -> conv maps in d_ws ----------------
// grid: sbk(768) * 4 t-quarters; block 256. LDS ~25KB -> 6 blocks/CU.
__global__ __launch_bounds__(256)
void k1_corr(const float* __restrict__ frames, const float* __restrict__ digit,
             float* __restrict__ conv)
{
    __shared__ float fr[FPX * 65];
    __shared__ float tmpl[DPX * DPX];
    __shared__ float cur[NP];

    const int tid = threadIdx.x;
    const int blk = blockIdx.x;
    const int tq  = blk & 3;
    const int sbk = blk >> 2;                  // ((s*NB+b)*NK + k)
    const int b   = (sbk / NK) % NB;

    const float* dg = digit + (size_t)sbk * (DPX * DPX);
    for (int i = tid; i < DPX * DPX; i += 256) tmpl[i] = dg[i];

    for (int tl = 0; tl < 5; ++tl) {
        const int t = tq * 5 + tl;
        __syncthreads();   // protects cur (copy done) and fr reuse
        const float* fp = frames + (size_t)(b * NT + t) * (FPX * FPX);
        for (int i = tid; i < FPX * FPX; i += 256)
            fr[(i >> 6) * 65 + (i & 63)] = fp[i];
        __syncthreads();

        for (int task = tid; task < 259; task += 256) {
            int g  = task / 37;
            int i  = task - g * 37;
            int j0 = g * 6;
            float a0 = 0.f, a1 = 0.f, a2 = 0.f, a3 = 0.f, a4 = 0.f, a5 = 0.f;
            for (int u = 0; u < DPX; ++u) {
                const float* frow = &fr[(i + u) * 65 + j0];
                float w[34];
#pragma unroll
                for (int x = 0; x < 34; ++x) w[x] = frow[x];
#pragma unroll
                for (int v = 0; v < DPX; ++v) {
                    float tv = tmpl[u * DPX + v];   // wave-uniform broadcast
                    a0 = fmaf(w[v + 0], tv, a0);
                    a1 = fmaf(w[v + 1], tv, a1);
                    a2 = fmaf(w[v + 2], tv, a2);
                    a3 = fmaf(w[v + 3], tv, a3);
                    a4 = fmaf(w[v + 4], tv, a4);
                    a5 = fmaf(w[v + 5], tv, a5);
                }
            }
            int base = i * CPX + j0;
            cur[base + 0] = a0;
            if (g != 6) {
                cur[base + 1] = a1; cur[base + 2] = a2; cur[base + 3] = a3;
                cur[base + 4] = a4; cur[base + 5] = a5;
            }
        }
        __syncthreads();
        float* grow = conv + ((size_t)sbk * NT + t) * NP;
        for (int i = tid; i < NP; i += 256) grow[i] = cur[i];
    }
}

// ---------------- Kernel 2: softmax+enc heads (role A) and diff+disp head (role B) ----
// grid: 3072 (1536 A + 1536 B); block 512. dyn LDS 80780 B -> 2 blocks/CU.
#define L_ROWS 0
#define L_HID  (11 * NP)            // 15059
#define L_MID  (L_HID + 10 * NH)    // 17619
#define L_STAT (L_MID + 2 * 10 * NHH)  // 20179
#define L_TOT  (L_STAT + 16)        // 20195 floats

__global__ __launch_bounds__(512)
void k2_mlp(const float* __restrict__ conv,
            const float* __restrict__ w_h1, const float* __restrict__ b_h1,
            const float* __restrict__ wm1,  const float* __restrict__ bm1,
            const float* __restrict__ wm2,  const float* __restrict__ bm2,
            const float* __restrict__ ws1,  const float* __restrict__ bs1,
            const float* __restrict__ ws2,  const float* __restrict__ bs2,
            const float* __restrict__ wd1,  const float* __restrict__ bd1,
            const float* __restrict__ wd2,  const float* __restrict__ bd2,
            const float* __restrict__ wd3,  const float* __restrict__ bd3,
            float* __restrict__ out)
{
    extern __shared__ float pool[];
    float* rows = pool + L_ROWS;
    float* hid  = pool + L_HID;
    float* mid  = pool + L_MID;
    float* stat = pool + L_STAT;

    const int tid  = threadIdx.x;
    const int lane = tid & 63;
    const int wv   = tid >> 6;

    const bool roleB = (blockIdx.x >= 1536);
    const int  idx   = roleB ? (blockIdx.x - 1536) : blockIdx.x;
    const int  sbk   = idx >> 1;
    const int  half  = idx & 1;
    const int  k = sbk % NK, b = (sbk / NK) % NB, s = sbk / (NK * NB);

    if (!roleB) {
        // ---- load 10 conv rows (t = half*10 .. +9) ----
        const float* src = conv + ((size_t)sbk * NT + half * 10) * NP;
        for (int i = tid; i < 10 * NP; i += 512) rows[i] = src[i];
        __syncthreads();

        // ---- per-row softmax, wave-local, in place ----
        for (int r = wv; r < 10; r += 8) {
            float* rp = rows + r * NP;
            float lmax = -3.0e38f;
            for (int i = lane; i < NP; i += 64) lmax = fmaxf(lmax, rp[i]);
            for (int o = 32; o; o >>= 1) lmax = fmaxf(lmax, __shfl_xor(lmax, o, 64));
            float lsum = 0.f;
            for (int i = lane; i < NP; i += 64) {
                float e = __expf(rp[i] - lmax);
                rp[i] = e;
                lsum += e;
            }
            for (int o = 32; o; o >>= 1) lsum += __shfl_xor(lsum, o, 64);
            if (lane == 0) stat[r] = 1.0f / lsum;
        }
        __syncthreads();

        // ---- hidden = relu(e @ w_h1 * inv + b), col = tid&255, 5 rows/thread ----
        {
            const int col = tid & 255, sub = tid >> 8, r0 = sub * 5;
            float acc[5] = {0.f, 0.f, 0.f, 0.f, 0.f};
            const float* wc = w_h1 + col;
            const float* er = rows + r0 * NP;
#pragma unroll 4
            for (int p = 0; p < NP; ++p) {
                float w = wc[(size_t)p * NH];
                acc[0] = fmaf(er[p],          w, acc[0]);
                acc[1] = fmaf(er[NP + p],     w, acc[1]);
                acc[2] = fmaf(er[2 * NP + p], w, acc[2]);
                acc[3] = fmaf(er[3 * NP + p], w, acc[3]);
                acc[4] = fmaf(er[4 * NP + p], w, acc[4]);
            }
            float bb = b_h1[col];
#pragma unroll
            for (int i = 0; i < 5; ++i) {
                float v = acc[i] * stat[r0 + i] + bb;
                hid[(r0 + i) * NH + col] = v > 0.f ? v : 0.f;
            }
        }
        __syncthreads();

        // ---- mid layers: sub2 0,1 -> mean rows 0-4/5-9; 2,3 -> std ----
        {
            const int j = tid & 127, sub2 = tid >> 7;
            const int br = sub2 >> 1, r0b = (sub2 & 1) * 5;
            const float* w1  = br ? ws1 : wm1;
            const float* b1v = br ? bs1 : bm1;
            float acc[5] = {0.f, 0.f, 0.f, 0.f, 0.f};
            const float* hr = hid + r0b * NH;
#pragma unroll 4
            for (int h = 0; h < NH; ++h) {
                float w = w1[h * NHH + j];
                acc[0] = fmaf(hr[h],          w, acc[0]);
                acc[1] = fmaf(hr[NH + h],     w, acc[1]);
                acc[2] = fmaf(hr[2 * NH + h], w, acc[2]);
                acc[3] = fmaf(hr[3 * NH + h], w, acc[3]);
                acc[4] = fmaf(hr[4 * NH + h], w, acc[4]);
            }
            float bb = b1v[j];
#pragma unroll
            for (int i = 0; i < 5; ++i) {
                float v = acc[i] + bb;
                mid[br * (10 * NHH) + (r0b + i) * NHH + j] = v > 0.f ? v : 0.f;
            }
        }
        __syncthreads();

        // ---- final heads: 10 rows x 2 branches x 2 dims ----
        if (tid < 40) {
            const int r = tid >> 2, br = (tid >> 1) & 1, d = tid & 1;
            const float* mb = mid + br * (10 * NHH) + r * NHH;
            const float* w2 = br ? ws2 : wm2;
            const float* b2 = br ? bs2 : bm2;
            float acc = 0.f;
            for (int j = 0; j < NHH; ++j) acc = fmaf(mb[j], w2[j * 2 + d], acc);
            acc += b2[d];
            const int tg = half * 10 + r;
            size_t oi = (((size_t)(s * NB + b) * NT + tg) * NK + k) * 2 + d;
            if (br == 0) out[oi] = tanhf(acc);
            else         out[30720 + oi] = __expf(acc);
        }
    } else {
        // ---- role B: temporal-diff path ----
        const int RL = half ? 10 : 11;       // conv rows loaded
        const int RD = half ? 9  : 10;       // diff rows produced
        const float* src = conv + ((size_t)sbk * NT + half * 10) * NP;
        for (int i = tid; i < RL * NP; i += 512) rows[i] = src[i];
        __syncthreads();

        // in-place diff along t (each thread owns column p)
        for (int p = tid; p < NP; p += 512) {
            float prev = rows[p];
            for (int r = 1; r < RL; ++r) {
                float c = rows[r * NP + p];
                rows[r * NP + p] = c - prev;
                prev = c;
            }
        }
        __syncthreads();

        // ---- dh1 = relu(diff @ wd1 + b) ----
        {
            const int col = tid & 255, sub = tid >> 8, r0 = sub * 5;
            float acc[5] = {0.f, 0.f, 0.f, 0.f, 0.f};
            const float* wc = wd1 + col;
            const float* er = rows + (r0 + 1) * NP;
#pragma unroll 4
            for (int p = 0; p < NP; ++p) {
                float w = wc[(size_t)p * NH];
                acc[0] = fmaf(er[p],          w, acc[0]);
                acc[1] = fmaf(er[NP + p],     w, acc[1]);
                acc[2] = fmaf(er[2 * NP + p], w, acc[2]);
                acc[3] = fmaf(er[3 * NP + p], w, acc[3]);
                acc[4] = fmaf(er[4 * NP + p], w, acc[4]);
            }
            float bb = bd1[col];
#pragma unroll
            for (int i = 0; i < 5; ++i) {
                int dr = r0 + i;
                if (dr < RD) {
                    float v = acc[i] + bb;
                    hid[dr * NH + col] = v > 0.f ? v : 0.f;
                }
            }
        }
        __syncthreads();

        // ---- dh2 = relu(dh1 @ wd2 + b): sub2 handles rows {sub2, sub2+4, sub2+8} ----
        {
            const int j = tid & 127, sub2 = tid >> 7;
            float acc[3] = {0.f, 0.f, 0.f};
#pragma unroll 4
            for (int h = 0; h < NH; ++h) {
                float w = wd2[h * NHH + j];
                acc[0] = fmaf(hid[sub2 * NH + h],       w, acc[0]);
                acc[1] = fmaf(hid[(sub2 + 4) * NH + h], w, acc[1]);
                acc[2] = fmaf(hid[(sub2 + 8) * NH + h], w, acc[2]);
            }
            float bb = bd2[j];
#pragma unroll
            for (int i = 0; i < 3; ++i) {
                int dr = sub2 + 4 * i;
                if (dr < RD) {
                    float v = acc[i] + bb;
                    mid[dr * NHH + j] = v > 0.f ? v : 0.f;
                }
            }
        }
        __syncthreads();

        // ---- disp output ----
        if (tid < 20) {
            const int dr = tid >> 1, d = tid & 1;
            if (dr < RD) {
                float acc = 0.f;
                const float* mb = mid + dr * NHH;
                for (int j = 0; j < NHH; ++j) acc = fmaf(mb[j], wd3[j * 2 + d], acc);
                acc += bd3[d];
                const int orow = half * 10 + dr;   // = t-1
                size_t oi = 61440 +
                    (((size_t)(s * NB + b) * (NT - 1) + orow) * NK + k) * 2 + d;
                out[oi] = tanhf(acc);
            }
        }
    }
}

extern "C" void kernel_launch(void* const* d_in, const int* in_sizes, int n_in,
                              void* d_out, int out_size, void* d_ws, size_t ws_size,
                              hipStream_t stream) {
    const float* frames = (const float*)d_in[0];
    const float* digit  = (const float*)d_in[1];
    const float* w_h1   = (const float*)d_in[2];
    const float* b_h1   = (const float*)d_in[3];
    const float* wm1    = (const float*)d_in[4];
    const float* bm1    = (const float*)d_in[5];
    const float* wm2    = (const float*)d_in[6];
    const float* bm2    = (const float*)d_in[7];
    const float* ws1    = (const float*)d_in[8];
    const float* bs1    = (const float*)d_in[9];
    const float* ws2    = (const float*)d_in[10];
    const float* bs2    = (const float*)d_in[11];
    const float* wd1    = (const float*)d_in[12];
    const float* bd1    = (const float*)d_in[13];
    const float* wd2    = (const float*)d_in[14];
    const float* bd2    = (const float*)d_in[15];
    const float* wd3    = (const float*)d_in[16];
    const float* bd3    = (const float*)d_in[17];

    float* conv = (float*)d_ws;        // 768*20*1369 floats = 84.1 MB
    float* o    = (float*)d_out;

    k1_corr<<<dim3(768 * 4), dim3(256), 0, stream>>>(frames, digit, conv);

    size_t smem = (size_t)L_TOT * sizeof(float);
    k2_mlp<<<dim3(3072), dim3(512), smem, stream>>>(conv,
        w_h1, b_h1, wm1, bm1, wm2, bm2, ws1, bs1, ws2, bs2,
        wd1, bd1, wd2, bd2, wd3, bd3, o);
}

// Round 4
// 1205.790 us; speedup vs baseline: 4.2138x; 1.6058x over previous
//
#include <hip/hip_runtime.h>

#define NS 16
#define NB 16
#define NK 3
#define NT 20
#define FPX 64
#define DPX 28
#define CPX 37
#define NP 1369
#define NPS 1372          /* padded row stride (16B-aligned) */
#define NH 256
#define NHH 128

// ================= Kernel 1: template correlation =================
// grid: sbk(768) * 4 t-quarters; block 192 (185 tasks: 5 col-groups x 37 rows).
__global__ __launch_bounds__(192)
void k1_corr(const float* __restrict__ frames, const float* __restrict__ digit,
             float* __restrict__ conv)
{
    __shared__ float fr[FPX * 65];        // odd stride: conflict-free row-strided reads
    __shared__ float tmpl[DPX * DPX];     // 784, f4-aligned rows (28 floats)
    __shared__ float cur[NPS];

    const int tid = threadIdx.x;
    const int blk = blockIdx.x;
    const int tq  = blk & 3;
    const int sbk = blk >> 2;
    const int b   = (sbk / NK) % NB;

    // stage template (float4)
    {
        const float4* dg4 = (const float4*)(digit + (size_t)sbk * (DPX * DPX));
        float4* t4 = (float4*)tmpl;
        for (int i = tid; i < (DPX * DPX) / 4; i += 192) t4[i] = dg4[i];
    }

    for (int tl = 0; tl < 5; ++tl) {
        const int t = tq * 5 + tl;
        __syncthreads();   // cur copied, fr reusable
        // stage frame: float4 global load -> 4 scalar LDS writes (odd LDS stride)
        {
            const float4* fp4 = (const float4*)(frames + (size_t)(b * NT + t) * (FPX * FPX));
            for (int idx = tid; idx < (FPX * FPX) / 4; idx += 192) {
                float4 v = fp4[idx];
                int r = idx >> 4, c = (idx & 15) * 4;
                float* d = &fr[r * 65 + c];
                d[0] = v.x; d[1] = v.y; d[2] = v.z; d[3] = v.w;
            }
        }
        __syncthreads();

        if (tid < 185) {
            const int g  = tid / 37;
            const int i  = tid - g * 37;
            const int j0 = g * 8;
            float a[8];
#pragma unroll
            for (int r = 0; r < 8; ++r) a[r] = 0.f;

            for (int u = 0; u < DPX; ++u) {
                const float* frow = &fr[(i + u) * 65 + j0];
                float w[35];
#pragma unroll
                for (int x = 0; x < 35; ++x) w[x] = frow[x];   // conflict-free scalar reads
                const float4* t4 = (const float4*)&tmpl[u * DPX];
#pragma unroll
                for (int x = 0; x < 7; ++x) {
                    float4 tv = t4[x];                          // broadcast f4
                    const int v = 4 * x;
#pragma unroll
                    for (int r = 0; r < 8; ++r) a[r] = fmaf(w[v + 0 + r], tv.x, a[r]);
#pragma unroll
                    for (int r = 0; r < 8; ++r) a[r] = fmaf(w[v + 1 + r], tv.y, a[r]);
#pragma unroll
                    for (int r = 0; r < 8; ++r) a[r] = fmaf(w[v + 2 + r], tv.z, a[r]);
#pragma unroll
                    for (int r = 0; r < 8; ++r) a[r] = fmaf(w[v + 3 + r], tv.w, a[r]);
                }
            }
            const int ncol = (g == 4) ? 5 : 8;
            for (int r = 0; r < ncol; ++r) cur[i * CPX + j0 + r] = a[r];
        }
        __syncthreads();
        // copy cur -> conv (float4, padded stride)
        {
            float4* grow4 = (float4*)(conv + ((size_t)sbk * NT + t) * NPS);
            const float4* c4 = (const float4*)cur;
            for (int idx = tid; idx < NPS / 4; idx += 192) grow4[idx] = c4[idx];
        }
    }
}

// ================= Kernel 2: merged MLP block per (sbk, half) =================
// block 512. LDS: rows[11*1372] + hid[10*256] + midB[10*128] + stat[16] = 74KB -> 2/CU.
#define L_ROWS 0
#define L_HID  (11 * NPS)            // 15092
#define L_MIDB (L_HID + 10 * NH)     // 17652
#define L_STAT (L_MIDB + 10 * NHH)   // 18932
#define L_TOT  (L_STAT + 16)         // 18948 floats = 75792 B

__global__ __launch_bounds__(512)
void k2_mlp(const float* __restrict__ conv,
            const float* __restrict__ w_h1, const float* __restrict__ b_h1,
            const float* __restrict__ wm1,  const float* __restrict__ bm1,
            const float* __restrict__ wm2,  const float* __restrict__ bm2,
            const float* __restrict__ ws1,  const float* __restrict__ bs1,
            const float* __restrict__ ws2,  const float* __restrict__ bs2,
            const float* __restrict__ wd1,  const float* __restrict__ bd1,
            const float* __restrict__ wd2,  const float* __restrict__ bd2,
            const float* __restrict__ wd3,  const float* __restrict__ bd3,
            float* __restrict__ out)
{
    extern __shared__ float pool[];
    float* rows = pool + L_ROWS;
    float* hid  = pool + L_HID;
    float* midB = pool + L_MIDB;
    float* stat = pool + L_STAT;

    const int tid  = threadIdx.x;
    const int lane = tid & 63;
    const int wv   = tid >> 6;

    const int sbk  = blockIdx.x >> 1;
    const int half = blockIdx.x & 1;
    const int k = sbk % NK, b = (sbk / NK) % NB, s = sbk / (NK * NB);

    const int RL   = half ? 10 : 11;     // conv rows loaded
    const int DCNT = half ? 9  : 10;     // valid diffs (d = 1..DCNT)

    // ---- stage conv rows (straight f4 copy, padded stride matches) ----
    {
        const float4* src4 = (const float4*)(conv + ((size_t)sbk * NT + half * 10) * NPS);
        float4* dst4 = (float4*)rows;
        const int n4 = RL * (NPS / 4);
        for (int i = tid; i < n4; i += 512) dst4[i] = src4[i];
        if (half) {  // zero row 10 so the unconditional diff d=10 is finite
            float4 z = {0.f, 0.f, 0.f, 0.f};
            for (int i = tid; i < NPS / 4; i += 512) dst4[10 * (NPS / 4) + i] = z;
        }
    }
    __syncthreads();

    // ---- phase 2: dh1 = relu(diff @ wd1 + bd1), diff on the fly ----
    {
        const int col = tid & 255, sub = tid >> 8;        // diffs d = sub*5+1 .. +5
        const float* base = rows + (sub * 5) * NPS;
        const float* wc = wd1 + col;
        float acc[5] = {0.f, 0.f, 0.f, 0.f, 0.f};
        for (int p = 0; p < 1368; p += 8) {
            float w[8];
#pragma unroll
            for (int j = 0; j < 8; ++j) w[j] = wc[(p + j) * NH];
            float4 rA[6], rB[6];
#pragma unroll
            for (int r = 0; r < 6; ++r) {
                const float* rp = base + r * NPS + p;
                rA[r] = *(const float4*)rp;
                rB[r] = *(const float4*)(rp + 4);
            }
#pragma unroll
            for (int i = 0; i < 5; ++i) {
                acc[i] = fmaf(rA[i+1].x - rA[i].x, w[0], acc[i]);
                acc[i] = fmaf(rA[i+1].y - rA[i].y, w[1], acc[i]);
                acc[i] = fmaf(rA[i+1].z - rA[i].z, w[2], acc[i]);
                acc[i] = fmaf(rA[i+1].w - rA[i].w, w[3], acc[i]);
                acc[i] = fmaf(rB[i+1].x - rB[i].x, w[4], acc[i]);
                acc[i] = fmaf(rB[i+1].y - rB[i].y, w[5], acc[i]);
                acc[i] = fmaf(rB[i+1].z - rB[i].z, w[6], acc[i]);
                acc[i] = fmaf(rB[i+1].w - rB[i].w, w[7], acc[i]);
            }
        }
        {   // tail p = 1368
            float wt = wc[1368 * NH];
#pragma unroll
            for (int i = 0; i < 5; ++i)
                acc[i] = fmaf(base[(i+1) * NPS + 1368] - base[i * NPS + 1368], wt, acc[i]);
        }
        float bb = bd1[col];
#pragma unroll
        for (int i = 0; i < 5; ++i) {
            int d = sub * 5 + 1 + i;
            if (d <= DCNT) {
                float v = acc[i] + bb;
                hid[(d - 1) * NH + col] = v > 0.f ? v : 0.f;
            }
        }
    }
    __syncthreads();

    // ---- phase 3: dh2 = relu(dh1 @ wd2 + bd2) -> midB ----
    {
        const int j = tid & 127, sub4 = tid >> 7;      // rows sub4, sub4+4, sub4+8
        const float* wc = wd2 + j;
        float acc[3] = {0.f, 0.f, 0.f};
        for (int h = 0; h < NH; h += 8) {
            float w[8];
#pragma unroll
            for (int q = 0; q < 8; ++q) w[q] = wc[(h + q) * NHH];
#pragma unroll
            for (int i = 0; i < 3; ++i) {
                int r = sub4 + 4 * i;
                if (r < 10) {
                    const float* hp = hid + r * NH + h;
                    float4 hA = *(const float4*)hp, hB = *(const float4*)(hp + 4);
                    acc[i] = fmaf(hA.x, w[0], acc[i]); acc[i] = fmaf(hA.y, w[1], acc[i]);
                    acc[i] = fmaf(hA.z, w[2], acc[i]); acc[i] = fmaf(hA.w, w[3], acc[i]);
                    acc[i] = fmaf(hB.x, w[4], acc[i]); acc[i] = fmaf(hB.y, w[5], acc[i]);
                    acc[i] = fmaf(hB.z, w[6], acc[i]); acc[i] = fmaf(hB.w, w[7], acc[i]);
                }
            }
        }
        float bb = bd2[j];
#pragma unroll
        for (int i = 0; i < 3; ++i) {
            int r = sub4 + 4 * i;
            if (r < DCNT) {
                float v = acc[i] + bb;
                midB[r * NHH + j] = v > 0.f ? v : 0.f;
            }
        }
    }
    __syncthreads();

    // ---- phase 4: softmax in place (rows 0..9) + disp head output ----
    for (int r = wv; r < 10; r += 8) {
        float* rp = rows + r * NPS;
        float lmax = -3.0e38f;
        for (int i = lane; i < NP; i += 64) lmax = fmaxf(lmax, rp[i]);
        for (int o = 32; o; o >>= 1) lmax = fmaxf(lmax, __shfl_xor(lmax, o, 64));
        float lsum = 0.f;
        for (int i = lane; i < NP; i += 64) {
            float e = __expf(rp[i] - lmax);
            rp[i] = e;
            lsum += e;
        }
        for (int o = 32; o; o >>= 1) lsum += __shfl_xor(lsum, o, 64);
        if (lane == 0) stat[r] = 1.0f / lsum;
    }
    if (tid < 20) {
        const int dr = tid >> 1, d = tid & 1;
        if (dr < DCNT) {
            float acc = 0.f;
            const float* mb = midB + dr * NHH;
            for (int j = 0; j < NHH; ++j) acc = fmaf(mb[j], wd3[j * 2 + d], acc);
            acc += bd3[d];
            const int orow = half * 10 + dr;
            size_t oi = 61440 + (((size_t)(s * NB + b) * (NT - 1) + orow) * NK + k) * 2 + d;
            out[oi] = tanhf(acc);
        }
    }
    __syncthreads();

    // ---- phase 5: hidden = relu(softmax @ w_h1 * inv + b_h1) -> hid ----
    {
        const int col = tid & 255, sub = tid >> 8, r0 = sub * 5;
        const float* base = rows + r0 * NPS;
        const float* wc = w_h1 + col;
        float acc[5] = {0.f, 0.f, 0.f, 0.f, 0.f};
        for (int p = 0; p < 1368; p += 8) {
            float w[8];
#pragma unroll
            for (int j = 0; j < 8; ++j) w[j] = wc[(p + j) * NH];
#pragma unroll
            for (int i = 0; i < 5; ++i) {
                const float* rp = base + i * NPS + p;
                float4 rA = *(const float4*)rp, rB = *(const float4*)(rp + 4);
                acc[i] = fmaf(rA.x, w[0], acc[i]); acc[i] = fmaf(rA.y, w[1], acc[i]);
                acc[i] = fmaf(rA.z, w[2], acc[i]); acc[i] = fmaf(rA.w, w[3], acc[i]);
                acc[i] = fmaf(rB.x, w[4], acc[i]); acc[i] = fmaf(rB.y, w[5], acc[i]);
                acc[i] = fmaf(rB.z, w[6], acc[i]); acc[i] = fmaf(rB.w, w[7], acc[i]);
            }
        }
        {
            float wt = wc[1368 * NH];
#pragma unroll
            for (int i = 0; i < 5; ++i) acc[i] = fmaf(base[i * NPS + 1368], wt, acc[i]);
        }
        float bb = b_h1[col];
#pragma unroll
        for (int i = 0; i < 5; ++i) {
            float v = acc[i] * stat[r0 + i] + bb;
            hid[(r0 + i) * NH + col] = v > 0.f ? v : 0.f;
        }
    }
    __syncthreads();

    // ---- phase 6: mean/std mid layers -> rows area (rows now dead) ----
    {
        float* mid = rows;                              // [br*1280 + r*128 + j]
        const int j = tid & 127, sub2 = tid >> 7;
        const int br = sub2 >> 1, r0b = (sub2 & 1) * 5;
        const float* w1  = br ? ws1 : wm1;
        const float* b1v = br ? bs1 : bm1;
        const float* wc = w1 + j;
        float acc[5] = {0.f, 0.f, 0.f, 0.f, 0.f};
        for (int h = 0; h < NH; h += 8) {
            float w[8];
#pragma unroll
            for (int q = 0; q < 8; ++q) w[q] = wc[(h + q) * NHH];
#pragma unroll
            for (int i = 0; i < 5; ++i) {
                const float* hp = hid + (r0b + i) * NH + h;
                float4 hA = *(const float4*)hp, hB = *(const float4*)(hp + 4);
                acc[i] = fmaf(hA.x, w[0], acc[i]); acc[i] = fmaf(hA.y, w[1], acc[i]);
                acc[i] = fmaf(hA.z, w[2], acc[i]); acc[i] = fmaf(hA.w, w[3], acc[i]);
                acc[i] = fmaf(hB.x, w[4], acc[i]); acc[i] = fmaf(hB.y, w[5], acc[i]);
                acc[i] = fmaf(hB.z, w[6], acc[i]); acc[i] = fmaf(hB.w, w[7], acc[i]);
            }
        }
        float bb = b1v[j];
#pragma unroll
        for (int i = 0; i < 5; ++i) {
            float v = acc[i] + bb;
            mid[br * (10 * NHH) + (r0b + i) * NHH + j] = v > 0.f ? v : 0.f;
        }
    }
    __syncthreads();

    // ---- phase 7: q_mean / q_std heads ----
    if (tid < 40) {
        const float* mid = rows;
        const int r = tid >> 2, br = (tid >> 1) & 1, d = tid & 1;
        const float* mb = mid + br * (10 * NHH) + r * NHH;
        const float* w2 = br ? ws2 : wm2;
        const float* b2 = br ? bs2 : bm2;
        float acc = 0.f;
        for (int j = 0; j < NHH; ++j) acc = fmaf(mb[j], w2[j * 2 + d], acc);
        acc += b2[d];
        const int tg = half * 10 + r;
        size_t oi = (((size_t)(s * NB + b) * NT + tg) * NK + k) * 2 + d;
        if (br == 0) out[oi] = tanhf(acc);
        else         out[30720 + oi] = __expf(acc);
    }
}

extern "C" void kernel_launch(void* const* d_in, const int* in_sizes, int n_in,
                              void* d_out, int out_size, void* d_ws, size_t ws_size,
                              hipStream_t stream) {
    const float* frames = (const float*)d_in[0];
    const float* digit  = (const float*)d_in[1];
    const float* w_h1   = (const float*)d_in[2];
    const float* b_h1   = (const float*)d_in[3];
    const float* wm1    = (const float*)d_in[4];
    const float* bm1    = (const float*)d_in[5];
    const float* wm2    = (const float*)d_in[6];
    const float* bm2    = (const float*)d_in[7];
    const float* ws1    = (const float*)d_in[8];
    const float* bs1    = (const float*)d_in[9];
    const float* ws2    = (const float*)d_in[10];
    const float* bs2    = (const float*)d_in[11];
    const float* wd1    = (const float*)d_in[12];
    const float* bd1    = (const float*)d_in[13];
    const float* wd2    = (const float*)d_in[14];
    const float* bd2    = (const float*)d_in[15];
    const float* wd3    = (const float*)d_in[16];
    const float* bd3    = (const float*)d_in[17];

    float* conv = (float*)d_ws;        // 768*20*1372 floats = 84.25 MB
    float* o    = (float*)d_out;

    k1_corr<<<dim3(768 * 4), dim3(192), 0, stream>>>(frames, digit, conv);

    size_t smem = (size_t)L_TOT * sizeof(float);
    k2_mlp<<<dim3(768 * 2), dim3(512), smem, stream>>>(conv,
        w_h1, b_h1, wm1, bm1, wm2, bm2, ws1, bs1, ws2, bs2,
        wd1, bd1, wd2, bd2, wd3, bd3, o);
}

// Round 6
// 704.406 us; speedup vs baseline: 7.2131x; 1.7118x over previous
//
#include <hip/hip_runtime.h>
#include <hip/hip_fp16.h>

typedef __attribute__((ext_vector_type(8))) _Float16 half8;
typedef __attribute__((ext_vector_type(4))) float f32x4;

#define NP 1369
#define KP 1376          /* padded K: 43 tiles of 32 */
#define NKT 43
#define CPX 37
#define ROWS_A 15360     /* 768 sbk * 20 t  */
#define ROWS_D 14592     /* 768 sbk * 19 dt */

/* ws layout (ushort units). total = 84,033,536 B <= 84.25MB proven in R3/R4 */
#define PA_OFF   0
#define PD_OFF   (ROWS_A * KP)
#define PWH_OFF  (PD_OFF + ROWS_D * KP)
#define PWD_OFF  (PWH_OFF + NKT * 16 * 512)
#define PW2_OFF  (PWD_OFF + NKT * 16 * 512)
#define PWD2_OFF (PW2_OFF + 8 * 16 * 512)

__device__ __forceinline__ unsigned short f2h(float f) {
    __half h = __float2half(f);          // v_cvt_f16_f32, RNE
    return __half_as_ushort(h);
}

// ============ k0: pack weights into MFMA-B fragment layout (fp16) ============
// B-frag for mfma_f32_16x16x32_f16: lane l holds B[k = kt*32+(l>>4)*8+j][n = nt*16+(l&15)]
__global__ __launch_bounds__(256)
void k0_pack(const float* __restrict__ w_h1, const float* __restrict__ wd1,
             const float* __restrict__ wm1,  const float* __restrict__ ws1,
             const float* __restrict__ wd2,  unsigned short* __restrict__ wsu)
{
    int idx = blockIdx.x * 256 + threadIdx.x;      // 0..802815
    int local, mode;
    unsigned short* dst;
    if (idx < 352256)      { mode = 0; local = idx;          dst = wsu + PWH_OFF; }
    else if (idx < 704512) { mode = 1; local = idx - 352256; dst = wsu + PWD_OFF; }
    else if (idx < 770048) { mode = 2; local = idx - 704512; dst = wsu + PW2_OFF; }
    else                   { mode = 3; local = idx - 770048; dst = wsu + PWD2_OFF; }
    int j = local & 7, lane = (local >> 3) & 63, rest = local >> 9;
    int NTn = (mode == 3) ? 8 : 16;
    int nt = rest % NTn, kt = rest / NTn;
    int k = kt * 32 + ((lane >> 4) << 3) + j;
    int n = nt * 16 + (lane & 15);
    float v = 0.f;
    if (mode == 0)      { if (k < NP) v = w_h1[k * 256 + n]; }
    else if (mode == 1) { if (k < NP) v = wd1[k * 256 + n]; }
    else if (mode == 2) { v = (n < 128) ? wm1[k * 128 + n] : ws1[k * 128 + (n - 128)]; }
    else                { v = wd2[k * 128 + n]; }
    dst[local] = f2h(v);
}

// ============ k1: correlation + softmax/diff + fp16 emit ============
// grid 1536 = sbk*2 halves; block 192. half0: t 0..9; half1: t 9..19 (t=9 is prologue).
__global__ __launch_bounds__(192)
void k1_corr(const float* __restrict__ frames, const float* __restrict__ digit,
             unsigned short* __restrict__ wsu)
{
    __shared__ __align__(16) float fr[64 * 65];
    __shared__ __align__(16) float tmpl[28 * 28];
    __shared__ float cur[KP];
    __shared__ float prev[KP];
    __shared__ float red[8];

    const int tid = threadIdx.x, lane = tid & 63, wv = tid >> 6;
    const int half = blockIdx.x & 1, sbk = blockIdx.x >> 1;
    const int b = (sbk / 3) & 15;

    {   // stage template
        const float4* dg4 = (const float4*)(digit + (size_t)sbk * 784);
        for (int i = tid; i < 196; i += 192) ((float4*)tmpl)[i] = dg4[i];
    }
    for (int i = tid; i < KP; i += 192) cur[i] = 0.f;   // zero pads 1369..1375 (persist)

    const int tstart = half ? 9 : 0;
    const int tcnt   = half ? 11 : 10;

    for (int tl = 0; tl < tcnt; ++tl) {
        const int t = tstart + tl;
        const bool wr = (half == 0) || (tl > 0);
        __syncthreads();   // guard fr/cur reuse vs previous iteration consumers
        {   // stage frame (b, t)
            const float4* fp4 = (const float4*)(frames + (size_t)(b * 20 + t) * 4096);
            for (int i = tid; i < 1024; i += 192) {
                float4 v = fp4[i];
                int r = i >> 4, c = (i & 15) * 4;
                float* d = &fr[r * 65 + c];
                d[0] = v.x; d[1] = v.y; d[2] = v.z; d[3] = v.w;
            }
        }
        __syncthreads();

        if (tid < 185) {   // correlation: 5 col-groups of 8 x 37 rows
            const int g  = tid / 37;
            const int i  = tid - g * 37;
            const int j0 = g * 8;
            float a[8];
#pragma unroll
            for (int r = 0; r < 8; ++r) a[r] = 0.f;
            for (int u = 0; u < 28; ++u) {
                const float* frow = &fr[(i + u) * 65 + j0];
                float w[35];
#pragma unroll
                for (int x = 0; x < 35; ++x) w[x] = frow[x];
                const float4* t4 = (const float4*)&tmpl[u * 28];
#pragma unroll
                for (int x = 0; x < 7; ++x) {
                    float4 tv = t4[x];
                    const int v = 4 * x;
#pragma unroll
                    for (int r = 0; r < 8; ++r) a[r] = fmaf(w[v + 0 + r], tv.x, a[r]);
#pragma unroll
                    for (int r = 0; r < 8; ++r) a[r] = fmaf(w[v + 1 + r], tv.y, a[r]);
#pragma unroll
                    for (int r = 0; r < 8; ++r) a[r] = fmaf(w[v + 2 + r], tv.z, a[r]);
#pragma unroll
                    for (int r = 0; r < 8; ++r) a[r] = fmaf(w[v + 3 + r], tv.w, a[r]);
                }
            }
            const int ncol = (g == 4) ? 5 : 8;
            for (int r = 0; r < ncol; ++r) cur[i * CPX + j0 + r] = a[r];
        }
        __syncthreads();

        if (wr) {
            // ---- diff -> PD (fp16) + prev=cur, same thread partition (no race) ----
            unsigned short* pdrow = wsu + PD_OFF + (size_t)(sbk * 19 + (t - 1)) * KP;
            for (int i2 = tid; i2 < 688; i2 += 192) {
                int p = i2 * 2;
                float c0 = cur[p], c1 = cur[p + 1];
                if (t > 0) {
                    unsigned int pk = (unsigned int)f2h(c0 - prev[p])
                                    | ((unsigned int)f2h(c1 - prev[p + 1]) << 16);
                    ((unsigned int*)pdrow)[i2] = pk;
                }
                prev[p] = c0; prev[p + 1] = c1;
            }
            // ---- softmax (fp32) -> PA (fp16) ----
            float lmax = -3.0e38f;
            for (int p = tid; p < NP; p += 192) lmax = fmaxf(lmax, cur[p]);
            for (int o = 32; o; o >>= 1) lmax = fmaxf(lmax, __shfl_xor(lmax, o, 64));
            if (lane == 0) red[wv] = lmax;
            __syncthreads();   // also orders prev-copy before cur exp-overwrite
            const float mx = fmaxf(fmaxf(red[0], red[1]), red[2]);
            float lsum = 0.f;
            for (int p = tid; p < NP; p += 192) {
                float e = __expf(cur[p] - mx);
                cur[p] = e;
                lsum += e;
            }
            for (int o = 32; o; o >>= 1) lsum += __shfl_xor(lsum, o, 64);
            if (lane == 0) red[4 + wv] = lsum;
            __syncthreads();
            const float inv = 1.0f / (red[4] + red[5] + red[6]);
            unsigned short* parow = wsu + PA_OFF + (size_t)(sbk * 20 + t) * KP;
            for (int i2 = tid; i2 < 688; i2 += 192) {
                int p = i2 * 2;
                unsigned int pk = (unsigned int)f2h(cur[p] * inv)
                                | ((unsigned int)f2h(cur[p + 1] * inv) << 16);
                ((unsigned int*)parow)[i2] = pk;
            }
        } else {
            for (int p = tid; p < KP; p += 192) prev[p] = cur[p];
        }
    }
}

// ============ k2_gemm1: [probs|diffs] @ [w_h1|wd1] + bias, relu -> fp16 in place ============
// grid 234 (120 A-path + 114 B-path); 256 thr; wave w owns M-tiles {2w, 2w+1}.
__global__ __launch_bounds__(256)
void k2_gemm1(unsigned short* __restrict__ wsu,
              const float* __restrict__ b_h1, const float* __restrict__ bd1)
{
    __shared__ __align__(16) unsigned short Bs[16 * 512];
    __shared__ __align__(16) unsigned short As[128 * 40];

    const int tid = threadIdx.x, l = tid & 63, w = tid >> 6;
    const bool pA = blockIdx.x < 120;
    const int M0 = pA ? blockIdx.x * 128 : (blockIdx.x - 120) * 128;
    unsigned short* Abase = wsu + (pA ? PA_OFF : PD_OFF);
    const unsigned short* PW = wsu + (pA ? PWH_OFF : PWD_OFF);
    const float* bias = pA ? b_h1 : bd1;

    f32x4 acc[2][16];
#pragma unroll
    for (int m = 0; m < 2; ++m)
#pragma unroll
        for (int n = 0; n < 16; ++n) acc[m][n] = (f32x4){0.f, 0.f, 0.f, 0.f};

    for (int kt = 0; kt < NKT; ++kt) {
        __syncthreads();
        {   // stage B tile (16KB)
            const int4* src = (const int4*)(PW + (size_t)kt * 8192 + tid * 32);
            int4* dst = (int4*)(Bs + tid * 32);
#pragma unroll
            for (int c = 0; c < 4; ++c) dst[c] = src[c];
        }
        {   // stage A tile 128 rows x 32 k (padded stride 40)
#pragma unroll
            for (int c = 0; c < 2; ++c) {
                int q = tid * 2 + c;
                int row = q >> 2, seg = q & 3;
                const int4* s = (const int4*)(Abase + (size_t)(M0 + row) * KP + kt * 32 + seg * 8);
                *(int4*)(As + row * 40 + seg * 8) = *s;
            }
        }
        __syncthreads();
        half8 af0 = *(const half8*)(As + ((w * 2 + 0) * 16 + (l & 15)) * 40 + (l >> 4) * 8);
        half8 af1 = *(const half8*)(As + ((w * 2 + 1) * 16 + (l & 15)) * 40 + (l >> 4) * 8);
#pragma unroll
        for (int nt = 0; nt < 16; ++nt) {
            half8 bf = *(const half8*)(Bs + nt * 512 + l * 8);
            acc[0][nt] = __builtin_amdgcn_mfma_f32_16x16x32_f16(af0, bf, acc[0][nt], 0, 0, 0);
            acc[1][nt] = __builtin_amdgcn_mfma_f32_16x16x32_f16(af1, bf, acc[1][nt], 0, 0, 0);
        }
    }
    // epilogue: bias + relu + fp16, in-place (cols 0..255 of rows this block owns)
#pragma unroll
    for (int m = 0; m < 2; ++m) {
        const int mt = w * 2 + m;
#pragma unroll
        for (int nt = 0; nt < 16; ++nt) {
            const int col = nt * 16 + (l & 15);
            const float bv = bias[col];
#pragma unroll
            for (int r = 0; r < 4; ++r) {
                const int row = M0 + mt * 16 + (l >> 4) * 4 + r;
                float v = acc[m][nt][r] + bv;
                v = v > 0.f ? v : 0.f;
                Abase[(size_t)row * KP + col] = f2h(v);
            }
        }
    }
}

// ============ k2_heads: second GEMM (K=256) + in-register final heads ============
template <bool PATHA>
__global__ __launch_bounds__(256)
void k2_heads(unsigned short* __restrict__ wsu,
              const float* __restrict__ b1a, const float* __restrict__ b1b,
              const float* __restrict__ w2a, const float* __restrict__ b2a,
              const float* __restrict__ w2b, const float* __restrict__ b2b,
              float* __restrict__ out)
{
    constexpr int NT2 = PATHA ? 16 : 8;
    __shared__ __align__(16) unsigned short Bs[16 * 512];
    const int tid = threadIdx.x, l = tid & 63, w = tid >> 6;
    const int M0 = blockIdx.x * 128;
    unsigned short* Abase = wsu + (PATHA ? PA_OFF : PD_OFF);
    const unsigned short* PW = wsu + (PATHA ? PW2_OFF : PWD2_OFF);
    const int c = l & 15;

    f32x4 acc[2][NT2];
#pragma unroll
    for (int m = 0; m < 2; ++m)
#pragma unroll
        for (int n = 0; n < NT2; ++n) acc[m][n] = (f32x4){0.f, 0.f, 0.f, 0.f};

    for (int kt = 0; kt < 8; ++kt) {
        __syncthreads();
        {
            const int4* src = (const int4*)(PW + (size_t)kt * (NT2 * 512) + tid * (NT2 * 2));
            int4* dst = (int4*)(Bs + tid * (NT2 * 2));
#pragma unroll
            for (int cc = 0; cc < NT2 / 4; ++cc) dst[cc] = src[cc];
        }
        __syncthreads();
        half8 af0 = *(const half8*)(Abase + (size_t)(M0 + (w * 2 + 0) * 16 + c) * KP + kt * 32 + (l >> 4) * 8);
        half8 af1 = *(const half8*)(Abase + (size_t)(M0 + (w * 2 + 1) * 16 + c) * KP + kt * 32 + (l >> 4) * 8);
#pragma unroll
        for (int nt = 0; nt < NT2; ++nt) {
            half8 bf = *(const half8*)(Bs + nt * 512 + l * 8);
            acc[0][nt] = __builtin_amdgcn_mfma_f32_16x16x32_f16(af0, bf, acc[0][nt], 0, 0, 0);
            acc[1][nt] = __builtin_amdgcn_mfma_f32_16x16x32_f16(af1, bf, acc[1][nt], 0, 0, 0);
        }
    }
    // bias + relu -> mid (in registers)
#pragma unroll
    for (int m = 0; m < 2; ++m)
#pragma unroll
        for (int nt = 0; nt < NT2; ++nt) {
            float bv;
            if (PATHA) bv = (nt < 8) ? b1a[nt * 16 + c] : b1b[(nt - 8) * 16 + c];
            else       bv = b1a[nt * 16 + c];
#pragma unroll
            for (int r = 0; r < 4; ++r) {
                float v = acc[m][nt][r] + bv;
                acc[m][nt][r] = v > 0.f ? v : 0.f;
            }
        }
    // head partials: dot over 128 cols (nt 0..7 [+8 for std]), lane holds col c of each nt
    float pm[2][2][4], ps[2][2][4];
#pragma unroll
    for (int m = 0; m < 2; ++m)
#pragma unroll
        for (int d = 0; d < 2; ++d)
#pragma unroll
            for (int r = 0; r < 4; ++r) { pm[m][d][r] = 0.f; ps[m][d][r] = 0.f; }
#pragma unroll
    for (int d = 0; d < 2; ++d)
#pragma unroll
        for (int nt = 0; nt < 8; ++nt) {
            const float wmv = w2a[(nt * 16 + c) * 2 + d];
            float wsv = 0.f;
            if (PATHA) wsv = w2b[(nt * 16 + c) * 2 + d];
#pragma unroll
            for (int m = 0; m < 2; ++m)
#pragma unroll
                for (int r = 0; r < 4; ++r) {
                    pm[m][d][r] = fmaf(acc[m][nt][r], wmv, pm[m][d][r]);
                    if (PATHA) ps[m][d][r] = fmaf(acc[m][nt + 8][r], wsv, ps[m][d][r]);
                }
        }
#pragma unroll
    for (int o = 1; o < 16; o <<= 1)
#pragma unroll
        for (int m = 0; m < 2; ++m)
#pragma unroll
            for (int d = 0; d < 2; ++d)
#pragma unroll
                for (int r = 0; r < 4; ++r) {
                    pm[m][d][r] += __shfl_xor(pm[m][d][r], o, 64);
                    if (PATHA) ps[m][d][r] += __shfl_xor(ps[m][d][r], o, 64);
                }
    if (c == 0) {
#pragma unroll
        for (int m = 0; m < 2; ++m)
#pragma unroll
            for (int r = 0; r < 4; ++r) {
                const int row = M0 + (w * 2 + m) * 16 + (l >> 4) * 4 + r;
                if (PATHA) {
                    const int sbk = row / 20, t = row % 20;
                    const int sb = sbk / 3, kk = sbk % 3;
                    const int oi = ((sb * 20 + t) * 3 + kk) * 2;
                    out[oi + 0] = tanhf(pm[m][0][r] + b2a[0]);
                    out[oi + 1] = tanhf(pm[m][1][r] + b2a[1]);
                    out[30720 + oi + 0] = __expf(ps[m][0][r] + b2b[0]);
                    out[30720 + oi + 1] = __expf(ps[m][1][r] + b2b[1]);
                } else {
                    const int sbk = row / 19, dt = row % 19;
                    const int sb = sbk / 3, kk = sbk % 3;
                    const int oi = 61440 + ((sb * 19 + dt) * 3 + kk) * 2;
                    out[oi + 0] = tanhf(pm[m][0][r] + b2a[0]);
                    out[oi + 1] = tanhf(pm[m][1][r] + b2a[1]);
                }
            }
    }
}

extern "C" void kernel_launch(void* const* d_in, const int* in_sizes, int n_in,
                              void* d_out, int out_size, void* d_ws, size_t ws_size,
                              hipStream_t stream) {
    const float* frames = (const float*)d_in[0];
    const float* digit  = (const float*)d_in[1];
    const float* w_h1   = (const float*)d_in[2];
    const float* b_h1   = (const float*)d_in[3];
    const float* wm1    = (const float*)d_in[4];
    const float* bm1    = (const float*)d_in[5];
    const float* wm2    = (const float*)d_in[6];
    const float* bm2    = (const float*)d_in[7];
    const float* ws1    = (const float*)d_in[8];
    const float* bs1    = (const float*)d_in[9];
    const float* ws2    = (const float*)d_in[10];
    const float* bs2    = (const float*)d_in[11];
    const float* wd1    = (const float*)d_in[12];
    const float* bd1    = (const float*)d_in[13];
    const float* wd2    = (const float*)d_in[14];
    const float* bd2    = (const float*)d_in[15];
    const float* wd3    = (const float*)d_in[16];
    const float* bd3    = (const float*)d_in[17];

    unsigned short* wsu = (unsigned short*)d_ws;
    float* o = (float*)d_out;

    k0_pack<<<dim3(3136), dim3(256), 0, stream>>>(w_h1, wd1, wm1, ws1, wd2, wsu);
    k1_corr<<<dim3(1536), dim3(192), 0, stream>>>(frames, digit, wsu);
    k2_gemm1<<<dim3(234), dim3(256), 0, stream>>>(wsu, b_h1, bd1);
    k2_heads<true><<<dim3(120), dim3(256), 0, stream>>>(wsu, bm1, bs1, wm2, bm2, ws2, bs2, o);
    k2_heads<false><<<dim3(114), dim3(256), 0, stream>>>(wsu, bd2, nullptr, wd3, bd3, nullptr, nullptr, o);
}

// Round 7
// 525.545 us; speedup vs baseline: 9.6680x; 1.3403x over previous
//
#include <hip/hip_runtime.h>
#include <hip/hip_fp16.h>

typedef __attribute__((ext_vector_type(8))) _Float16 half8;
typedef __attribute__((ext_vector_type(2))) _Float16 h2f;
typedef __attribute__((ext_vector_type(4))) float f32x4;

#define NP 1369
#define KP 1376          /* padded K: 43 tiles of 32 */
#define NKT 43
#define CPX 37
#define ROWS_A 15360     /* 768 sbk * 20 t  */
#define ROWS_D 14592     /* 768 sbk * 19 dt */

/* ws layout (ushort units). total = 84,033,536 B <= 84.25MB proven in R3/R4 */
#define PA_OFF   0
#define PD_OFF   (ROWS_A * KP)
#define PWH_OFF  (PD_OFF + ROWS_D * KP)
#define PWD_OFF  (PWH_OFF + NKT * 16 * 512)
#define PW2_OFF  (PWD_OFF + NKT * 16 * 512)
#define PWD2_OFF (PW2_OFF + 8 * 16 * 512)

__device__ __forceinline__ unsigned short f2h(float f) {
    __half h = __float2half(f);          // v_cvt_f16_f32, RNE
    return __half_as_ushort(h);
}
__device__ __forceinline__ h2f u2h2(unsigned int u) {
    h2f r; __builtin_memcpy(&r, &u, 4); return r;
}

// ============ k0: pack weights into MFMA-B fragment layout (fp16) ============
__global__ __launch_bounds__(256)
void k0_pack(const float* __restrict__ w_h1, const float* __restrict__ wd1,
             const float* __restrict__ wm1,  const float* __restrict__ ws1,
             const float* __restrict__ wd2,  unsigned short* __restrict__ wsu)
{
    int idx = blockIdx.x * 256 + threadIdx.x;      // 0..802815
    int local, mode;
    unsigned short* dst;
    if (idx < 352256)      { mode = 0; local = idx;          dst = wsu + PWH_OFF; }
    else if (idx < 704512) { mode = 1; local = idx - 352256; dst = wsu + PWD_OFF; }
    else if (idx < 770048) { mode = 2; local = idx - 704512; dst = wsu + PW2_OFF; }
    else                   { mode = 3; local = idx - 770048; dst = wsu + PWD2_OFF; }
    int j = local & 7, lane = (local >> 3) & 63, rest = local >> 9;
    int NTn = (mode == 3) ? 8 : 16;
    int nt = rest % NTn, kt = rest / NTn;
    int k = kt * 32 + ((lane >> 4) << 3) + j;
    int n = nt * 16 + (lane & 15);
    float v = 0.f;
    if (mode == 0)      { if (k < NP) v = w_h1[k * 256 + n]; }
    else if (mode == 1) { if (k < NP) v = wd1[k * 256 + n]; }
    else if (mode == 2) { v = (n < 128) ? wm1[k * 128 + n] : ws1[k * 128 + (n - 128)]; }
    else                { v = wd2[k * 128 + n]; }
    dst[local] = f2h(v);
}

// ============ k1: fp16/dot2 correlation + softmax/diff + fp16 emit ============
// grid 1536 = sbk*2 halves; block 192. half0: t 0..9; half1: t 9..19 (t=9 prologue).
__global__ __launch_bounds__(192)
void k1_corr(const float* __restrict__ frames, const float* __restrict__ digit,
             unsigned short* __restrict__ wsu)
{
    __shared__ __align__(16) unsigned int frd[64 * 36];   // fp16 frame pairs, 36 dw/row
    __shared__ __align__(16) unsigned int t2d[28 * 16];   // aligned template pairs
    __shared__ __align__(16) unsigned int t2sd[28 * 16];  // shifted template pairs
    __shared__ float cur[KP];
    __shared__ float prev[KP];
    __shared__ float red[8];

    const int tid = threadIdx.x, lane = tid & 63, wv = tid >> 6;
    const int half = blockIdx.x & 1, sbk = blockIdx.x >> 1;
    const int b = (sbk / 3) & 15;

    // ---- template staging: T2[u][m]=(T[2m],T[2m+1]); T2s[u][m]=(T[2m-1],T[2m]) ----
    {
        const float* trow0 = digit + (size_t)sbk * 784;
        for (int slot = tid; slot < 28 * 32; slot += 192) {
            int u = slot >> 5, q = slot & 31;
            const float* trow = trow0 + u * 28;
            unsigned short lo, hi;
            if (q < 16) {
                lo = (q < 14) ? f2h(trow[2 * q]) : (unsigned short)0;
                hi = (q < 14) ? f2h(trow[2 * q + 1]) : (unsigned short)0;
                t2d[u * 16 + q] = (unsigned)lo | ((unsigned)hi << 16);
            } else {
                int m = q - 16;
                lo = (m >= 1 && m <= 14) ? f2h(trow[2 * m - 1]) : (unsigned short)0;
                hi = (m < 14) ? f2h(trow[2 * m]) : (unsigned short)0;
                t2sd[u * 16 + m] = (unsigned)lo | ((unsigned)hi << 16);
            }
        }
    }
    for (int i = tid; i < 64 * 36; i += 192) frd[i] = 0;   // pads (dw 32..35) stay 0
    for (int i = tid; i < KP; i += 192) cur[i] = 0.f;      // zero K-pads (persist)

    const int tstart = half ? 9 : 0;
    const int tcnt   = half ? 11 : 10;

    for (int tl = 0; tl < tcnt; ++tl) {
        const int t = tstart + tl;
        const bool wr = (half == 0) || (tl > 0);
        __syncthreads();   // guard frd/cur reuse vs previous iteration consumers
        {   // stage frame (b, t): fp32 -> packed fp16 pairs
            const float4* fp4 = (const float4*)(frames + (size_t)(b * 20 + t) * 4096);
            for (int idx = tid; idx < 1024; idx += 192) {
                float4 v = fp4[idx];
                int r = idx >> 4, c4 = idx & 15;
                unsigned lo = (unsigned)f2h(v.x) | ((unsigned)f2h(v.y) << 16);
                unsigned hi = (unsigned)f2h(v.z) | ((unsigned)f2h(v.w) << 16);
                *(uint2*)&frd[r * 36 + c4 * 2] = make_uint2(lo, hi);
            }
        }
        __syncthreads();

        if (tid < 185) {   // 5 col-groups of 8 x 37 rows
            const int g  = tid / 37;
            const int i  = tid - g * 37;
            const int j0d = g * 4;                   // dword col base (= 8 halfs)
            float a[8];
#pragma unroll
            for (int r = 0; r < 8; ++r) a[r] = 0.f;

            for (int u = 0; u < 28; ++u) {
                const uint4* fq = (const uint4*)&frd[(i + u) * 36 + j0d];
                uint4 f0 = fq[0], f1 = fq[1], f2v = fq[2], f3v = fq[3], f4v = fq[4];
                unsigned w2[20] = {f0.x, f0.y, f0.z, f0.w, f1.x, f1.y, f1.z, f1.w,
                                   f2v.x, f2v.y, f2v.z, f2v.w, f3v.x, f3v.y, f3v.z, f3v.w,
                                   f4v.x, f4v.y, f4v.z, f4v.w};
                const uint4* tq  = (const uint4*)&t2d[u * 16];
                const uint4* tsq = (const uint4*)&t2sd[u * 16];
                uint4 ta = tq[0], tb = tq[1], tcv = tq[2], tdv = tq[3];
                uint4 sa = tsq[0], sb = tsq[1], sc = tsq[2], sd = tsq[3];
                unsigned t2r[14]  = {ta.x, ta.y, ta.z, ta.w, tb.x, tb.y, tb.z, tb.w,
                                     tcv.x, tcv.y, tcv.z, tcv.w, tdv.x, tdv.y};
                unsigned t2sr[15] = {sa.x, sa.y, sa.z, sa.w, sb.x, sb.y, sb.z, sb.w,
                                     sc.x, sc.y, sc.z, sc.w, sd.x, sd.y, sd.z};
#pragma unroll
                for (int r = 0; r < 8; r += 2) {
#pragma unroll
                    for (int m = 0; m < 14; ++m)
                        a[r] = __builtin_amdgcn_fdot2(u2h2(w2[r / 2 + m]),
                                                      u2h2(t2r[m]), a[r], false);
                }
#pragma unroll
                for (int r = 1; r < 8; r += 2) {
#pragma unroll
                    for (int m = 0; m < 15; ++m)
                        a[r] = __builtin_amdgcn_fdot2(u2h2(w2[(r - 1) / 2 + m]),
                                                      u2h2(t2sr[m]), a[r], false);
                }
            }
            const int ncol = (g == 4) ? 5 : 8;
#pragma unroll
            for (int r = 0; r < 8; ++r)
                if (r < ncol) cur[i * CPX + g * 8 + r] = a[r];
        }
        __syncthreads();

        if (wr) {
            // ---- diff -> PD (fp16) + prev=cur, same thread partition (no race) ----
            unsigned short* pdrow = wsu + PD_OFF + (size_t)(sbk * 19 + (t - 1)) * KP;
            for (int i2 = tid; i2 < 688; i2 += 192) {
                int p = i2 * 2;
                float c0 = cur[p], c1 = cur[p + 1];
                if (t > 0) {
                    unsigned int pk = (unsigned int)f2h(c0 - prev[p])
                                    | ((unsigned int)f2h(c1 - prev[p + 1]) << 16);
                    ((unsigned int*)pdrow)[i2] = pk;
                }
                prev[p] = c0; prev[p + 1] = c1;
            }
            // ---- softmax (fp32) -> PA (fp16) ----
            float lmax = -3.0e38f;
            for (int p = tid; p < NP; p += 192) lmax = fmaxf(lmax, cur[p]);
            for (int o = 32; o; o >>= 1) lmax = fmaxf(lmax, __shfl_xor(lmax, o, 64));
            if (lane == 0) red[wv] = lmax;
            __syncthreads();   // also orders prev-copy before cur exp-overwrite
            const float mx = fmaxf(fmaxf(red[0], red[1]), red[2]);
            float lsum = 0.f;
            for (int p = tid; p < NP; p += 192) {
                float e = __expf(cur[p] - mx);
                cur[p] = e;
                lsum += e;
            }
            for (int o = 32; o; o >>= 1) lsum += __shfl_xor(lsum, o, 64);
            if (lane == 0) red[4 + wv] = lsum;
            __syncthreads();
            const float inv = 1.0f / (red[4] + red[5] + red[6]);
            unsigned short* parow = wsu + PA_OFF + (size_t)(sbk * 20 + t) * KP;
            for (int i2 = tid; i2 < 688; i2 += 192) {
                int p = i2 * 2;
                unsigned int pk = (unsigned int)f2h(cur[p] * inv)
                                | ((unsigned int)f2h(cur[p + 1] * inv) << 16);
                ((unsigned int*)parow)[i2] = pk;
            }
        } else {
            for (int p = tid; p < KP; p += 192) prev[p] = cur[p];
        }
    }
}

// ============ k2_gemm1: [probs|diffs] @ [w_h1|wd1] + bias, relu -> fp16 in place ============
__global__ __launch_bounds__(256)
void k2_gemm1(unsigned short* __restrict__ wsu,
              const float* __restrict__ b_h1, const float* __restrict__ bd1)
{
    __shared__ __align__(16) unsigned short Bs[16 * 512];
    __shared__ __align__(16) unsigned short As[128 * 40];

    const int tid = threadIdx.x, l = tid & 63, w = tid >> 6;
    const bool pA = blockIdx.x < 120;
    const int M0 = pA ? blockIdx.x * 128 : (blockIdx.x - 120) * 128;
    unsigned short* Abase = wsu + (pA ? PA_OFF : PD_OFF);
    const unsigned short* PW = wsu + (pA ? PWH_OFF : PWD_OFF);
    const float* bias = pA ? b_h1 : bd1;

    f32x4 acc[2][16];
#pragma unroll
    for (int m = 0; m < 2; ++m)
#pragma unroll
        for (int n = 0; n < 16; ++n) acc[m][n] = (f32x4){0.f, 0.f, 0.f, 0.f};

    for (int kt = 0; kt < NKT; ++kt) {
        __syncthreads();
        {   // stage B tile (16KB)
            const int4* src = (const int4*)(PW + (size_t)kt * 8192 + tid * 32);
            int4* dst = (int4*)(Bs + tid * 32);
#pragma unroll
            for (int c = 0; c < 4; ++c) dst[c] = src[c];
        }
        {   // stage A tile 128 rows x 32 k (padded stride 40)
#pragma unroll
            for (int c = 0; c < 2; ++c) {
                int q = tid * 2 + c;
                int row = q >> 2, seg = q & 3;
                const int4* s = (const int4*)(Abase + (size_t)(M0 + row) * KP + kt * 32 + seg * 8);
                *(int4*)(As + row * 40 + seg * 8) = *s;
            }
        }
        __syncthreads();
        half8 af0 = *(const half8*)(As + ((w * 2 + 0) * 16 + (l & 15)) * 40 + (l >> 4) * 8);
        half8 af1 = *(const half8*)(As + ((w * 2 + 1) * 16 + (l & 15)) * 40 + (l >> 4) * 8);
#pragma unroll
        for (int nt = 0; nt < 16; ++nt) {
            half8 bf = *(const half8*)(Bs + nt * 512 + l * 8);
            acc[0][nt] = __builtin_amdgcn_mfma_f32_16x16x32_f16(af0, bf, acc[0][nt], 0, 0, 0);
            acc[1][nt] = __builtin_amdgcn_mfma_f32_16x16x32_f16(af1, bf, acc[1][nt], 0, 0, 0);
        }
    }
#pragma unroll
    for (int m = 0; m < 2; ++m) {
        const int mt = w * 2 + m;
#pragma unroll
        for (int nt = 0; nt < 16; ++nt) {
            const int col = nt * 16 + (l & 15);
            const float bv = bias[col];
#pragma unroll
            for (int r = 0; r < 4; ++r) {
                const int row = M0 + mt * 16 + (l >> 4) * 4 + r;
                float v = acc[m][nt][r] + bv;
                v = v > 0.f ? v : 0.f;
                Abase[(size_t)row * KP + col] = f2h(v);
            }
        }
    }
}

// ============ k2_heads: second GEMM (K=256) + in-register final heads ============
template <bool PATHA>
__global__ __launch_bounds__(256)
void k2_heads(unsigned short* __restrict__ wsu,
              const float* __restrict__ b1a, const float* __restrict__ b1b,
              const float* __restrict__ w2a, const float* __restrict__ b2a,
              const float* __restrict__ w2b, const float* __restrict__ b2b,
              float* __restrict__ out)
{
    constexpr int NT2 = PATHA ? 16 : 8;
    __shared__ __align__(16) unsigned short Bs[16 * 512];
    const int tid = threadIdx.x, l = tid & 63, w = tid >> 6;
    const int M0 = blockIdx.x * 128;
    unsigned short* Abase = wsu + (PATHA ? PA_OFF : PD_OFF);
    const unsigned short* PW = wsu + (PATHA ? PW2_OFF : PWD2_OFF);
    const int c = l & 15;

    f32x4 acc[2][NT2];
#pragma unroll
    for (int m = 0; m < 2; ++m)
#pragma unroll
        for (int n = 0; n < NT2; ++n) acc[m][n] = (f32x4){0.f, 0.f, 0.f, 0.f};

    for (int kt = 0; kt < 8; ++kt) {
        __syncthreads();
        {
            const int4* src = (const int4*)(PW + (size_t)kt * (NT2 * 512) + tid * (NT2 * 2));
            int4* dst = (int4*)(Bs + tid * (NT2 * 2));
#pragma unroll
            for (int cc = 0; cc < NT2 / 4; ++cc) dst[cc] = src[cc];
        }
        __syncthreads();
        half8 af0 = *(const half8*)(Abase + (size_t)(M0 + (w * 2 + 0) * 16 + c) * KP + kt * 32 + (l >> 4) * 8);
        half8 af1 = *(const half8*)(Abase + (size_t)(M0 + (w * 2 + 1) * 16 + c) * KP + kt * 32 + (l >> 4) * 8);
#pragma unroll
        for (int nt = 0; nt < NT2; ++nt) {
            half8 bf = *(const half8*)(Bs + nt * 512 + l * 8);
            acc[0][nt] = __builtin_amdgcn_mfma_f32_16x16x32_f16(af0, bf, acc[0][nt], 0, 0, 0);
            acc[1][nt] = __builtin_amdgcn_mfma_f32_16x16x32_f16(af1, bf, acc[1][nt], 0, 0, 0);
        }
    }
#pragma unroll
    for (int m = 0; m < 2; ++m)
#pragma unroll
        for (int nt = 0; nt < NT2; ++nt) {
            float bv;
            if (PATHA) bv = (nt < 8) ? b1a[nt * 16 + c] : b1b[(nt - 8) * 16 + c];
            else       bv = b1a[nt * 16 + c];
#pragma unroll
            for (int r = 0; r < 4; ++r) {
                float v = acc[m][nt][r] + bv;
                acc[m][nt][r] = v > 0.f ? v : 0.f;
            }
        }
    float pm[2][2][4], ps[2][2][4];
#pragma unroll
    for (int m = 0; m < 2; ++m)
#pragma unroll
        for (int d = 0; d < 2; ++d)
#pragma unroll
            for (int r = 0; r < 4; ++r) { pm[m][d][r] = 0.f; ps[m][d][r] = 0.f; }
#pragma unroll
    for (int d = 0; d < 2; ++d)
#pragma unroll
        for (int nt = 0; nt < 8; ++nt) {
            const float wmv = w2a[(nt * 16 + c) * 2 + d];
            float wsv = 0.f;
            if (PATHA) wsv = w2b[(nt * 16 + c) * 2 + d];
#pragma unroll
            for (int m = 0; m < 2; ++m)
#pragma unroll
                for (int r = 0; r < 4; ++r) {
                    pm[m][d][r] = fmaf(acc[m][nt][r], wmv, pm[m][d][r]);
                    if (PATHA) ps[m][d][r] = fmaf(acc[m][nt + 8][r], wsv, ps[m][d][r]);
                }
        }
#pragma unroll
    for (int o = 1; o < 16; o <<= 1)
#pragma unroll
        for (int m = 0; m < 2; ++m)
#pragma unroll
            for (int d = 0; d < 2; ++d)
#pragma unroll
                for (int r = 0; r < 4; ++r) {
                    pm[m][d][r] += __shfl_xor(pm[m][d][r], o, 64);
                    if (PATHA) ps[m][d][r] += __shfl_xor(ps[m][d][r], o, 64);
                }
    if (c == 0) {
#pragma unroll
        for (int m = 0; m < 2; ++m)
#pragma unroll
            for (int r = 0; r < 4; ++r) {
                const int row = M0 + (w * 2 + m) * 16 + (l >> 4) * 4 + r;
                if (PATHA) {
                    const int sbk = row / 20, t = row % 20;
                    const int sb = sbk / 3, kk = sbk % 3;
                    const int oi = ((sb * 20 + t) * 3 + kk) * 2;
                    out[oi + 0] = tanhf(pm[m][0][r] + b2a[0]);
                    out[oi + 1] = tanhf(pm[m][1][r] + b2a[1]);
                    out[30720 + oi + 0] = __expf(ps[m][0][r] + b2b[0]);
                    out[30720 + oi + 1] = __expf(ps[m][1][r] + b2b[1]);
                } else {
                    const int sbk = row / 19, dt = row % 19;
                    const int sb = sbk / 3, kk = sbk % 3;
                    const int oi = 61440 + ((sb * 19 + dt) * 3 + kk) * 2;
                    out[oi + 0] = tanhf(pm[m][0][r] + b2a[0]);
                    out[oi + 1] = tanhf(pm[m][1][r] + b2a[1]);
                }
            }
    }
}

extern "C" void kernel_launch(void* const* d_in, const int* in_sizes, int n_in,
                              void* d_out, int out_size, void* d_ws, size_t ws_size,
                              hipStream_t stream) {
    const float* frames = (const float*)d_in[0];
    const float* digit  = (const float*)d_in[1];
    const float* w_h1   = (const float*)d_in[2];
    const float* b_h1   = (const float*)d_in[3];
    const float* wm1    = (const float*)d_in[4];
    const float* bm1    = (const float*)d_in[5];
    const float* wm2    = (const float*)d_in[6];
    const float* bm2    = (const float*)d_in[7];
    const float* ws1    = (const float*)d_in[8];
    const float* bs1    = (const float*)d_in[9];
    const float* ws2    = (const float*)d_in[10];
    const float* bs2    = (const float*)d_in[11];
    const float* wd1    = (const float*)d_in[12];
    const float* bd1    = (const float*)d_in[13];
    const float* wd2    = (const float*)d_in[14];
    const float* bd2    = (const float*)d_in[15];
    const float* wd3    = (const float*)d_in[16];
    const float* bd3    = (const float*)d_in[17];

    unsigned short* wsu = (unsigned short*)d_ws;
    float* o = (float*)d_out;

    k0_pack<<<dim3(3136), dim3(256), 0, stream>>>(w_h1, wd1, wm1, ws1, wd2, wsu);
    k1_corr<<<dim3(1536), dim3(192), 0, stream>>>(frames, digit, wsu);
    k2_gemm1<<<dim3(234), dim3(256), 0, stream>>>(wsu, b_h1, bd1);
    k2_heads<true><<<dim3(120), dim3(256), 0, stream>>>(wsu, bm1, bs1, wm2, bm2, ws2, bs2, o);
    k2_heads<false><<<dim3(114), dim3(256), 0, stream>>>(wsu, bd2, nullptr, wd3, bd3, nullptr, nullptr, o);
}

// Round 8
// 232.857 us; speedup vs baseline: 21.8202x; 2.2569x over previous
//
#include <hip/hip_runtime.h>
#include <hip/hip_fp16.h>

typedef __attribute__((ext_vector_type(8))) _Float16 half8;
typedef __attribute__((ext_vector_type(2))) _Float16 h2f;
typedef __attribute__((ext_vector_type(4))) float f32x4;

#define NP 1369
#define KP 1376          /* padded row stride: 43 tiles of 32 / 86 tiles of 16 */
#define NKT 43
#define ROWS_A 15360     /* 768 sbk * 20 t  */
#define ROWS_D 14592     /* 768 sbk * 19 dt */

/* ws layout (ushort units). total incl tsum = 84,036,608 B <= 84.25MB proven */
#define PA_OFF   0
#define PD_OFF   (ROWS_A * KP)
#define PWH_OFF  (PD_OFF + ROWS_D * KP)
#define PWD_OFF  (PWH_OFF + NKT * 16 * 512)
#define PW2_OFF  (PWD_OFF + NKT * 16 * 512)
#define PWD2_OFF (PW2_OFF + 8 * 16 * 512)
#define TSUM_OFF (PWD2_OFF + 8 * 8 * 512)   /* 768 floats follow */

__device__ __forceinline__ unsigned short f2h(float f) {
    __half h = __float2half(f);
    return __half_as_ushort(h);
}
__device__ __forceinline__ h2f u2h2(unsigned int u) {
    h2f r; __builtin_memcpy(&r, &u, 4); return r;
}
__device__ __forceinline__ unsigned h2u(h2f h) {
    unsigned r; __builtin_memcpy(&r, &h, 4); return r;
}

// ============ k0: pack weights into MFMA-B fragment layout (fp16) ============
__global__ __launch_bounds__(256)
void k0_pack(const float* __restrict__ w_h1, const float* __restrict__ wd1,
             const float* __restrict__ wm1,  const float* __restrict__ ws1,
             const float* __restrict__ wd2,  unsigned short* __restrict__ wsu)
{
    int idx = blockIdx.x * 256 + threadIdx.x;      // 0..802815
    int local, mode;
    unsigned short* dst;
    if (idx < 352256)      { mode = 0; local = idx;          dst = wsu + PWH_OFF; }
    else if (idx < 704512) { mode = 1; local = idx - 352256; dst = wsu + PWD_OFF; }
    else if (idx < 770048) { mode = 2; local = idx - 704512; dst = wsu + PW2_OFF; }
    else                   { mode = 3; local = idx - 770048; dst = wsu + PWD2_OFF; }
    int j = local & 7, lane = (local >> 3) & 63, rest = local >> 9;
    int NTn = (mode == 3) ? 8 : 16;
    int nt = rest % NTn, kt = rest / NTn;
    int k = kt * 32 + ((lane >> 4) << 3) + j;
    int n = nt * 16 + (lane & 15);
    float v = 0.f;
    if (mode == 0)      { if (k < NP) v = w_h1[k * 256 + n]; }
    else if (mode == 1) { if (k < NP) v = wd1[k * 256 + n]; }
    else if (mode == 2) { v = (n < 128) ? wm1[k * 128 + n] : ws1[k * 128 + (n - 128)]; }
    else                { v = wd2[k * 128 + n]; }
    dst[local] = f2h(v);
}

// ============ k0b: per-template sum -> baseline C = 0.5 * sum(T) ============
__global__ __launch_bounds__(64)
void k0b_tsum(const float* __restrict__ digit, float* __restrict__ tsum)
{
    const int sbk = blockIdx.x, l = threadIdx.x;
    const float* tp = digit + (size_t)sbk * 784;
    float s = 0.f;
    for (int i = l; i < 784; i += 64) s += tp[i];
    for (int o = 32; o; o >>= 1) s += __shfl_xor(s, o, 64);
    if (l == 0) tsum[sbk] = 0.5f * s;
}

// ============ k1a: correlation as im2col MFMA GEMM ============
// grid 960 = (b 16) x (t 20) x (ntile 3); block 256 (4 waves).
// M=1369 positions (86 tiles), N=16 templates, K'=28 tiles (u*32+v, v>=28 zeroed in B).
__global__ __launch_bounds__(256, 4)
void k1a_corr(const float* __restrict__ frames, const float* __restrict__ digit,
              const float* __restrict__ tsum, unsigned short* __restrict__ wsu)
{
    __shared__ __align__(16) unsigned short Bs[28 * 512];  // 28,672 B
    __shared__ __align__(16) unsigned int frd[64 * 36];    // fp16 frame pairs, 9,216 B
    __shared__ float Cn[16];

    const int tid = threadIdx.x, l = tid & 63, w = tid >> 6;
    const int nt = blockIdx.x % 3;
    const int t  = (blockIdx.x / 3) % 20;
    const int bb = blockIdx.x / 60;
    const int N0 = nt * 16;

    // ---- stage B fragments: slot = kt*64 + lane ----
    for (int slot = tid; slot < 1792; slot += 256) {
        int kt = slot >> 6, sl = slot & 63;
        int n  = N0 + (sl & 15);
        int v0 = (sl >> 4) << 3;
        int sbk_n = ((n / 3) * 16 + bb) * 3 + (n % 3);
        const float* tp = digit + (size_t)sbk_n * 784 + kt * 28 + v0;
        float4 fa = *(const float4*)tp;
        float4 fb = (v0 <= 16) ? *(const float4*)(tp + 4) : make_float4(0.f, 0.f, 0.f, 0.f);
        uint4 pk;
        pk.x = (unsigned)f2h(fa.x) | ((unsigned)f2h(fa.y) << 16);
        pk.y = (unsigned)f2h(fa.z) | ((unsigned)f2h(fa.w) << 16);
        pk.z = (unsigned)f2h(fb.x) | ((unsigned)f2h(fb.y) << 16);
        pk.w = (unsigned)f2h(fb.z) | ((unsigned)f2h(fb.w) << 16);
        *(uint4*)(Bs + slot * 8) = pk;
    }
    // ---- baselines ----
    if (tid < 16) {
        int n = N0 + tid;
        int sbk_n = ((n / 3) * 16 + bb) * 3 + (n % 3);
        Cn[tid] = tsum[sbk_n];
    }
    // ---- stage frame as fp16 pairs; zero col-pads (dwords 32..35 per row) ----
    if (tid < 256) frd[(tid >> 2) * 36 + 32 + (tid & 3)] = 0u;
    {
        const float4* fp4 = (const float4*)(frames + (size_t)(bb * 20 + t) * 4096);
        for (int idx = tid; idx < 1024; idx += 256) {
            float4 v = fp4[idx];
            int r = idx >> 4, c4 = idx & 15;
            unsigned lo = (unsigned)f2h(v.x) | ((unsigned)f2h(v.y) << 16);
            unsigned hi = (unsigned)f2h(v.z) | ((unsigned)f2h(v.w) << 16);
            *(uint2*)&frd[r * 36 + c4 * 2] = make_uint2(lo, hi);
        }
    }
    __syncthreads();

    const int c15 = l & 15, quad = l >> 4, v0q = quad << 3;
    const int cntw = (89 - w) / 4;        // 22,22,21,21 tiles per wave

    for (int m0 = 0; m0 < cntw; m0 += 8) {
        const int tc = (cntw - m0 < 8) ? (cntw - m0) : 8;
        int baseb[8]; unsigned shv[8];
#pragma unroll
        for (int it = 0; it < 8; ++it) {
            int tI = w + 4 * (m0 + it);
            int p  = tI * 16 + c15;
            int pc = p > 1368 ? 1368 : p;
            int i  = pc / 37;
            int jj = pc - i * 37;
            int c  = jj + v0q;
            baseb[it] = i * 144 + (c >> 1) * 4;
            shv[it]   = (unsigned)((c & 1) << 4);
        }
        f32x4 acc[8];
#pragma unroll
        for (int it = 0; it < 8; ++it) acc[it] = (f32x4){0.f, 0.f, 0.f, 0.f};

        for (int kt = 0; kt < 28; ++kt) {
            half8 bf = *(const half8*)(Bs + kt * 512 + l * 8);
            const char* fbase = (const char*)frd + kt * 144;
#pragma unroll
            for (int it = 0; it < 8; ++it) {
                if (it < tc) {
                    const char* ap = fbase + baseb[it];
                    unsigned w0 = *(const unsigned*)(ap);
                    unsigned w1 = *(const unsigned*)(ap + 4);
                    unsigned w2 = *(const unsigned*)(ap + 8);
                    unsigned w3 = *(const unsigned*)(ap + 12);
                    unsigned w4 = *(const unsigned*)(ap + 16);
                    unsigned sh = shv[it];
                    union { unsigned u[4]; half8 h8; } af;
                    af.u[0] = (unsigned)(((((unsigned long long)w1) << 32) | w0) >> sh);
                    af.u[1] = (unsigned)(((((unsigned long long)w2) << 32) | w1) >> sh);
                    af.u[2] = (unsigned)(((((unsigned long long)w3) << 32) | w2) >> sh);
                    af.u[3] = (unsigned)(((((unsigned long long)w4) << 32) | w3) >> sh);
                    acc[it] = __builtin_amdgcn_mfma_f32_16x16x32_f16(af.h8, bf, acc[it], 0, 0, 0);
                }
            }
        }
        // ---- epilogue: conv - C -> fp16 into PA ----
        const float C = Cn[c15];
        const int n = N0 + c15;
        const int sbk_n = ((n / 3) * 16 + bb) * 3 + (n % 3);
        unsigned short* orow = wsu + PA_OFF + (size_t)(sbk_n * 20 + t) * KP;
#pragma unroll
        for (int it = 0; it < 8; ++it) {
            if (it < tc) {
                int tI = w + 4 * (m0 + it);
                int p0 = tI * 16 + quad * 4;
                if (p0 + 3 <= 1368) {
                    ushort4 st;
                    st.x = f2h(acc[it][0] - C); st.y = f2h(acc[it][1] - C);
                    st.z = f2h(acc[it][2] - C); st.w = f2h(acc[it][3] - C);
                    *(ushort4*)(orow + p0) = st;
                } else {
#pragma unroll
                    for (int r = 0; r < 4; ++r)
                        if (p0 + r <= 1368) orow[p0 + r] = f2h(acc[it][r] - C);
                }
            }
        }
    }
}

// ============ k1b: per-sbk diff -> PD and in-place softmax -> PA ============
// grid 768; block 256. LDS 20 rows x 1376 halfs = 55,040 B.
__global__ __launch_bounds__(256)
void k1b_sm(unsigned short* __restrict__ wsu)
{
    __shared__ __align__(16) unsigned short rows[20 * KP];
    const int tid = threadIdx.x, l = tid & 63, w = tid >> 6;
    const int sbk = blockIdx.x;
    unsigned short* pa = wsu + PA_OFF + (size_t)sbk * 20 * KP;
    unsigned short* pd = wsu + PD_OFF + (size_t)sbk * 19 * KP;

    for (int i = tid; i < 20 * 172; i += 256) {
        int r = i / 172, q = i - r * 172;
        *(uint4*)(rows + r * KP + q * 8) = *(const uint4*)(pa + (size_t)r * KP + q * 8);
    }
    __syncthreads();

    // ---- diffs: PD[d] = conv[d+1] - conv[d] (fp16 packed sub) ----
    for (int i = tid; i < 19 * 172; i += 256) {
        int d = i / 172, q = i - d * 172;
        const unsigned* c1 = (const unsigned*)(rows + (d + 1) * KP + q * 8);
        const unsigned* c0 = (const unsigned*)(rows + d * KP + q * 8);
        uint4 st;
        st.x = h2u(u2h2(c1[0]) - u2h2(c0[0]));
        st.y = h2u(u2h2(c1[1]) - u2h2(c0[1]));
        st.z = h2u(u2h2(c1[2]) - u2h2(c0[2]));
        st.w = h2u(u2h2(c1[3]) - u2h2(c0[3]));
        *(uint4*)(pd + (size_t)d * KP + q * 8) = st;
    }

    // ---- softmax per row (fp32 math), wave w owns rows w, w+4, ... ----
    for (int r = w; r < 20; r += 4) {
        const unsigned* rp = (const unsigned*)(rows + r * KP);
        float mx = -3.0e38f;
        for (int q = l; q < 685; q += 64) {
            unsigned v = rp[q];
            h2f h = u2h2(v);
            float f0 = (float)h[0], f1 = (float)h[1];
            if (q == 684) f1 = -3.0e38f;      // half 1369 is pad
            mx = fmaxf(mx, fmaxf(f0, f1));
        }
        for (int o = 32; o; o >>= 1) mx = fmaxf(mx, __shfl_xor(mx, o, 64));
        float sum = 0.f;
        for (int q = l; q < 685; q += 64) {
            unsigned v = rp[q];
            h2f h = u2h2(v);
            float e0 = __expf((float)h[0] - mx);
            float e1 = (q == 684) ? 0.f : __expf((float)h[1] - mx);
            sum += e0 + e1;
        }
        for (int o = 32; o; o >>= 1) sum += __shfl_xor(sum, o, 64);
        const float inv = 1.0f / sum;
        unsigned* prow = (unsigned*)(pa + (size_t)r * KP);
        for (int q = l; q < 685; q += 64) {
            unsigned v = rp[q];
            h2f h = u2h2(v);
            float e0 = __expf((float)h[0] - mx) * inv;
            float e1 = (q == 684) ? 0.f : __expf((float)h[1] - mx) * inv;
            prow[q] = (unsigned)f2h(e0) | ((unsigned)f2h(e1) << 16);
        }
    }
}

// ============ k2_gemm1: [probs|diffs] @ [w_h1|wd1] + bias, relu -> fp16 in place ============
__global__ __launch_bounds__(256)
void k2_gemm1(unsigned short* __restrict__ wsu,
              const float* __restrict__ b_h1, const float* __restrict__ bd1)
{
    __shared__ __align__(16) unsigned short Bsh[16 * 512];
    __shared__ __align__(16) unsigned short As[128 * 40];

    const int tid = threadIdx.x, l = tid & 63, w = tid >> 6;
    const bool pA = blockIdx.x < 120;
    const int M0 = pA ? blockIdx.x * 128 : (blockIdx.x - 120) * 128;
    unsigned short* Abase = wsu + (pA ? PA_OFF : PD_OFF);
    const unsigned short* PW = wsu + (pA ? PWH_OFF : PWD_OFF);
    const float* bias = pA ? b_h1 : bd1;

    f32x4 acc[2][16];
#pragma unroll
    for (int m = 0; m < 2; ++m)
#pragma unroll
        for (int n = 0; n < 16; ++n) acc[m][n] = (f32x4){0.f, 0.f, 0.f, 0.f};

    for (int kt = 0; kt < NKT; ++kt) {
        __syncthreads();
        {
            const int4* src = (const int4*)(PW + (size_t)kt * 8192 + tid * 32);
            int4* dst = (int4*)(Bsh + tid * 32);
#pragma unroll
            for (int c = 0; c < 4; ++c) dst[c] = src[c];
        }
        {
#pragma unroll
            for (int c = 0; c < 2; ++c) {
                int q = tid * 2 + c;
                int row = q >> 2, seg = q & 3;
                const int4* s = (const int4*)(Abase + (size_t)(M0 + row) * KP + kt * 32 + seg * 8);
                *(int4*)(As + row * 40 + seg * 8) = *s;
            }
        }
        __syncthreads();
        half8 af0 = *(const half8*)(As + ((w * 2 + 0) * 16 + (l & 15)) * 40 + (l >> 4) * 8);
        half8 af1 = *(const half8*)(As + ((w * 2 + 1) * 16 + (l & 15)) * 40 + (l >> 4) * 8);
#pragma unroll
        for (int nt = 0; nt < 16; ++nt) {
            half8 bf = *(const half8*)(Bsh + nt * 512 + l * 8);
            acc[0][nt] = __builtin_amdgcn_mfma_f32_16x16x32_f16(af0, bf, acc[0][nt], 0, 0, 0);
            acc[1][nt] = __builtin_amdgcn_mfma_f32_16x16x32_f16(af1, bf, acc[1][nt], 0, 0, 0);
        }
    }
#pragma unroll
    for (int m = 0; m < 2; ++m) {
        const int mt = w * 2 + m;
#pragma unroll
        for (int nt = 0; nt < 16; ++nt) {
            const int col = nt * 16 + (l & 15);
            const float bv = bias[col];
#pragma unroll
            for (int r = 0; r < 4; ++r) {
                const int row = M0 + mt * 16 + (l >> 4) * 4 + r;
                float v = acc[m][nt][r] + bv;
                v = v > 0.f ? v : 0.f;
                Abase[(size_t)row * KP + col] = f2h(v);
            }
        }
    }
}

// ============ k2_heads: second GEMM (K=256) + in-register final heads ============
template <bool PATHA>
__global__ __launch_bounds__(256)
void k2_heads(unsigned short* __restrict__ wsu,
              const float* __restrict__ b1a, const float* __restrict__ b1b,
              const float* __restrict__ w2a, const float* __restrict__ b2a,
              const float* __restrict__ w2b, const float* __restrict__ b2b,
              float* __restrict__ out)
{
    constexpr int NT2 = PATHA ? 16 : 8;
    __shared__ __align__(16) unsigned short Bsh[16 * 512];
    const int tid = threadIdx.x, l = tid & 63, w = tid >> 6;
    const int M0 = blockIdx.x * 128;
    unsigned short* Abase = wsu + (PATHA ? PA_OFF : PD_OFF);
    const unsigned short* PW = wsu + (PATHA ? PW2_OFF : PWD2_OFF);
    const int c = l & 15;

    f32x4 acc[2][NT2];
#pragma unroll
    for (int m = 0; m < 2; ++m)
#pragma unroll
        for (int n = 0; n < NT2; ++n) acc[m][n] = (f32x4){0.f, 0.f, 0.f, 0.f};

    for (int kt = 0; kt < 8; ++kt) {
        __syncthreads();
        {
            const int4* src = (const int4*)(PW + (size_t)kt * (NT2 * 512) + tid * (NT2 * 2));
            int4* dst = (int4*)(Bsh + tid * (NT2 * 2));
#pragma unroll
            for (int cc = 0; cc < NT2 / 4; ++cc) dst[cc] = src[cc];
        }
        __syncthreads();
        half8 af0 = *(const half8*)(Abase + (size_t)(M0 + (w * 2 + 0) * 16 + c) * KP + kt * 32 + (l >> 4) * 8);
        half8 af1 = *(const half8*)(Abase + (size_t)(M0 + (w * 2 + 1) * 16 + c) * KP + kt * 32 + (l >> 4) * 8);
#pragma unroll
        for (int nt = 0; nt < NT2; ++nt) {
            half8 bf = *(const half8*)(Bsh + nt * 512 + l * 8);
            acc[0][nt] = __builtin_amdgcn_mfma_f32_16x16x32_f16(af0, bf, acc[0][nt], 0, 0, 0);
            acc[1][nt] = __builtin_amdgcn_mfma_f32_16x16x32_f16(af1, bf, acc[1][nt], 0, 0, 0);
        }
    }
#pragma unroll
    for (int m = 0; m < 2; ++m)
#pragma unroll
        for (int nt = 0; nt < NT2; ++nt) {
            float bv;
            if (PATHA) bv = (nt < 8) ? b1a[nt * 16 + c] : b1b[(nt - 8) * 16 + c];
            else       bv = b1a[nt * 16 + c];
#pragma unroll
            for (int r = 0; r < 4; ++r) {
                float v = acc[m][nt][r] + bv;
                acc[m][nt][r] = v > 0.f ? v : 0.f;
            }
        }
    float pm[2][2][4], ps[2][2][4];
#pragma unroll
    for (int m = 0; m < 2; ++m)
#pragma unroll
        for (int d = 0; d < 2; ++d)
#pragma unroll
            for (int r = 0; r < 4; ++r) { pm[m][d][r] = 0.f; ps[m][d][r] = 0.f; }
#pragma unroll
    for (int d = 0; d < 2; ++d)
#pragma unroll
        for (int nt = 0; nt < 8; ++nt) {
            const float wmv = w2a[(nt * 16 + c) * 2 + d];
            float wsv = 0.f;
            if (PATHA) wsv = w2b[(nt * 16 + c) * 2 + d];
#pragma unroll
            for (int m = 0; m < 2; ++m)
#pragma unroll
                for (int r = 0; r < 4; ++r) {
                    pm[m][d][r] = fmaf(acc[m][nt][r], wmv, pm[m][d][r]);
                    if (PATHA) ps[m][d][r] = fmaf(acc[m][nt + 8][r], wsv, ps[m][d][r]);
                }
        }
#pragma unroll
    for (int o = 1; o < 16; o <<= 1)
#pragma unroll
        for (int m = 0; m < 2; ++m)
#pragma unroll
            for (int d = 0; d < 2; ++d)
#pragma unroll
                for (int r = 0; r < 4; ++r) {
                    pm[m][d][r] += __shfl_xor(pm[m][d][r], o, 64);
                    if (PATHA) ps[m][d][r] += __shfl_xor(ps[m][d][r], o, 64);
                }
    if (c == 0) {
#pragma unroll
        for (int m = 0; m < 2; ++m)
#pragma unroll
            for (int r = 0; r < 4; ++r) {
                const int row = M0 + (w * 2 + m) * 16 + (l >> 4) * 4 + r;
                if (PATHA) {
                    const int sbk = row / 20, t = row % 20;
                    const int sb = sbk / 3, kk = sbk % 3;
                    const int oi = ((sb * 20 + t) * 3 + kk) * 2;
                    out[oi + 0] = tanhf(pm[m][0][r] + b2a[0]);
                    out[oi + 1] = tanhf(pm[m][1][r] + b2a[1]);
                    out[30720 + oi + 0] = __expf(ps[m][0][r] + b2b[0]);
                    out[30720 + oi + 1] = __expf(ps[m][1][r] + b2b[1]);
                } else {
                    const int sbk = row / 19, dt = row % 19;
                    const int sb = sbk / 3, kk = sbk % 3;
                    const int oi = 61440 + ((sb * 19 + dt) * 3 + kk) * 2;
                    out[oi + 0] = tanhf(pm[m][0][r] + b2a[0]);
                    out[oi + 1] = tanhf(pm[m][1][r] + b2a[1]);
                }
            }
    }
}

extern "C" void kernel_launch(void* const* d_in, const int* in_sizes, int n_in,
                              void* d_out, int out_size, void* d_ws, size_t ws_size,
                              hipStream_t stream) {
    const float* frames = (const float*)d_in[0];
    const float* digit  = (const float*)d_in[1];
    const float* w_h1   = (const float*)d_in[2];
    const float* b_h1   = (const float*)d_in[3];
    const float* wm1    = (const float*)d_in[4];
    const float* bm1    = (const float*)d_in[5];
    const float* wm2    = (const float*)d_in[6];
    const float* bm2    = (const float*)d_in[7];
    const float* ws1    = (const float*)d_in[8];
    const float* bs1    = (const float*)d_in[9];
    const float* ws2    = (const float*)d_in[10];
    const float* bs2    = (const float*)d_in[11];
    const float* wd1    = (const float*)d_in[12];
    const float* bd1    = (const float*)d_in[13];
    const float* wd2    = (const float*)d_in[14];
    const float* bd2    = (const float*)d_in[15];
    const float* wd3    = (const float*)d_in[16];
    const float* bd3    = (const float*)d_in[17];

    unsigned short* wsu = (unsigned short*)d_ws;
    float* tsum = (float*)(wsu + TSUM_OFF);
    float* o = (float*)d_out;

    k0_pack<<<dim3(3136), dim3(256), 0, stream>>>(w_h1, wd1, wm1, ws1, wd2, wsu);
    k0b_tsum<<<dim3(768), dim3(64), 0, stream>>>(digit, tsum);
    k1a_corr<<<dim3(960), dim3(256), 0, stream>>>(frames, digit, tsum, wsu);
    k1b_sm<<<dim3(768), dim3(256), 0, stream>>>(wsu);
    k2_gemm1<<<dim3(234), dim3(256), 0, stream>>>(wsu, b_h1, bd1);
    k2_heads<true><<<dim3(120), dim3(256), 0, stream>>>(wsu, bm1, bs1, wm2, bm2, ws2, bs2, o);
    k2_heads<false><<<dim3(114), dim3(256), 0, stream>>>(wsu, bd2, nullptr, wd3, bd3, nullptr, nullptr, o);
}